// Round 4
// baseline (402.110 us; speedup 1.0000x reference)
//
#include <hip/hip_runtime.h>

using u16 = unsigned short;
typedef __bf16 bf16x8 __attribute__((ext_vector_type(8)));
typedef unsigned short u16x8 __attribute__((ext_vector_type(8)));
typedef float floatx4 __attribute__((ext_vector_type(4)));

__device__ __forceinline__ u16 f2bf(float f) {
  union { float f; unsigned u; } c; c.f = f;
  unsigned u = c.u;
  u += 0x7fffu + ((u >> 16) & 1u);   // round-to-nearest-even
  return (u16)(u >> 16);
}
__device__ __forceinline__ float bf2f(u16 h) {
  union { unsigned u; float f; } c; c.u = ((unsigned)h) << 16; return c.f;
}

__device__ __forceinline__ void st_out(float* p, float v) { *p = v; }
__device__ __forceinline__ void st_out(u16* p, float v) { *p = f2bf(v); }

__device__ __forceinline__ void load16(const u16* g, u16* l) {
  __builtin_amdgcn_global_load_lds(
      (const __attribute__((address_space(1))) void*)g,
      (__attribute__((address_space(3))) void*)l, 16, 0, 0);
}

#define TILE 128
#define BK 64

// ---------------------------------------------------------------------------
// Legacy 128x128 tile GEMM core (m97-structure) — used by rect/tri.
// LDS: row r's 8 16B-chunks XOR-permuted (slot = m ^ (r&7)) -> 0 bank conflicts.
// ---------------------------------------------------------------------------
template<typename OutT>
__device__ __forceinline__ void gemm_core(
    const u16* __restrict__ A, int lda, long sA,
    const u16* __restrict__ Bt, int ldb, long sB,
    OutT* __restrict__ C, int ldc, long sC,
    int kmax, int bx, int by, int bz, int tid)
{
  __shared__ u16 As[TILE * BK];
  __shared__ u16 Bs[TILE * BK];

  const u16* Ab = A + bz * sA + (long)by * TILE * lda;
  const u16* Bb = Bt + bz * sB + (long)bx * TILE * ldb;

  int lane = tid & 63;
  int wm = ((tid >> 7) & 1) * 64;
  int wn = ((tid >> 6) & 1) * 64;

  floatx4 acc[4][4] = {};
  int arow = wm + (lane & 15);
  int brow = wn + (lane & 15);
  int q = lane >> 4;

  for (int k0 = 0; k0 < kmax; k0 += BK) {
    __syncthreads();
#pragma unroll
    for (int h = 0; h < 4; h++) {
      int cc = tid + h * 256;
      int row = cc >> 3, gm = (cc & 7) ^ (row & 7);
      load16(Ab + (long)row * lda + k0 + gm * 8, &As[cc * 8]);
    }
#pragma unroll
    for (int h = 0; h < 4; h++) {
      int cc = tid + h * 256;
      int row = cc >> 3, gm = (cc & 7) ^ (row & 7);
      load16(Bb + (long)row * ldb + k0 + gm * 8, &Bs[cc * 8]);
    }
    __builtin_amdgcn_s_waitcnt(0);
    __syncthreads();

#pragma unroll
    for (int kp = 0; kp < 2; kp++) {
      bf16x8 a[4], b[4];
#pragma unroll
      for (int i = 0; i < 4; i++) {
        int r = arow + i * 16;
        a[i] = *(const bf16x8*)&As[(r * 8 + ((kp * 4 + q) ^ (r & 7))) * 8];
      }
#pragma unroll
      for (int j = 0; j < 4; j++) {
        int r = brow + j * 16;
        b[j] = *(const bf16x8*)&Bs[(r * 8 + ((kp * 4 + q) ^ (r & 7))) * 8];
      }
#pragma unroll
      for (int i = 0; i < 4; i++)
#pragma unroll
        for (int j = 0; j < 4; j++)
          acc[i][j] = __builtin_amdgcn_mfma_f32_16x16x32_bf16(a[i], b[j], acc[i][j], 0, 0, 0);
    }
  }

  // epilogue: C/D layout col=lane&15, row=(lane>>4)*4+reg  [m89-verified]
  OutT* Cb = C + bz * sC;
  int colbase = bx * TILE + wn + (lane & 15);
  int rowbase = by * TILE + wm + ((lane >> 4) << 2);
#pragma unroll
  for (int i = 0; i < 4; i++)
#pragma unroll
    for (int j = 0; j < 4; j++) {
      int col = colbase + j * 16;
#pragma unroll
      for (int r = 0; r < 4; r++)
        st_out(&Cb[(long)(rowbase + i * 16 + r) * ldc + col], acc[i][j][r]);
    }
}

// Small rectangular GEMM (used for NT), XCD-contiguous remap
template<typename OutT>
__global__ __launch_bounds__(256, 2)
void gemm_rect(const u16* __restrict__ A, int lda, long sA,
               const u16* __restrict__ Bt, int ldb, long sB,
               OutT* __restrict__ C, int ldc, long sC, int K,
               int l2gx, int nO8s)
{
  int L = blockIdx.x;
  int t = ((L & 7) << nO8s) | (L >> 3);
  int bx = t & ((1 << l2gx) - 1), by = t >> l2gx;
  gemm_core<OutT>(A, lda, sA, Bt, ldb, sB, C, ldc, sC, K, bx, by, blockIdx.y, threadIdx.x);
}

// Causal S = Y @ x^T -> bf16 scores (scale pre-folded into Wq). 136 tiles/batch.
// 2x2 super-block triangle walk (R3): per-XCD working set ~1 MB, L2-resident.
__global__ __launch_bounds__(256, 2)
void gemm_tri(const u16* __restrict__ A, int lda, long sA,
              const u16* __restrict__ Bt, int ldb, long sB,
              u16* __restrict__ C, int ldc, long sC, int K)
{
  int tp = blockIdx.x;                       // 0..135
  int g = (tp & 7) * 17 + (tp >> 3);         // 17 contiguous slots per XCD
  int sr = 0, sc = 0, pre = 0;
  for (;;) {
    int sz = (sr == sc) ? 3 : 4;
    if (pre + sz > g) break;
    pre += sz; ++sc;
    if (sc > sr) { ++sr; sc = 0; }
  }
  int w = g - pre;
  int r, c;
  if (sr == sc) { r = 2 * sr + (w > 0); c = 2 * sc + (w == 2); }
  else          { r = 2 * sr + (w >> 1); c = 2 * sc + (w & 1); }
  gemm_core<u16>(A, lda, sA, Bt, ldb, sB, C, ldc, sC, K, c, r, blockIdx.y, threadIdx.x);
}

// ---------------------------------------------------------------------------
// Row stats for softmax fusion: per row, m = causal max, inv = 1/sum(exp(v-m)).
// Same reduction path as the old softmax kernel -> numerically identical m,inv.
// Reads only the trimmed window [0, W); writes 8 B/row.
// ---------------------------------------------------------------------------
__global__ __launch_bounds__(256)
void rowstat(const u16* __restrict__ S, float2* __restrict__ MI)
{
  const int T = 2048;
  int row = blockIdx.x & (T - 1);
  const u16* Prow = S + (long)blockIdx.x * T;
  int n = row + 1;
  int W = ((row >> 7) + 1) << 7;
  int tid = threadIdx.x, lane = tid & 63, wid = tid >> 6;
  int i0 = tid * 8;
  bool act = (i0 < W);

  float v[8];
  float lmax = -3.0e38f;
  if (act) {
    u16x8 pv = *(const u16x8*)(Prow + i0);
#pragma unroll
    for (int j = 0; j < 8; j++) {
      v[j] = (i0 + j < n) ? bf2f(pv[j]) : -3.0e38f;
      lmax = fmaxf(lmax, v[j]);
    }
  }
  __shared__ float red[8];
#pragma unroll
  for (int o = 32; o > 0; o >>= 1) lmax = fmaxf(lmax, __shfl_down(lmax, o, 64));
  if (lane == 0) red[wid] = lmax;
  __syncthreads();
  float m = fmaxf(fmaxf(red[0], red[1]), fmaxf(red[2], red[3]));

  float lsum = 0.f;
  if (act) {
#pragma unroll
    for (int j = 0; j < 8; j++)
      lsum += (i0 + j < n) ? __expf(v[j] - m) : 0.f;
  }
#pragma unroll
  for (int o = 32; o > 0; o >>= 1) lsum += __shfl_down(lsum, o, 64);
  if (lane == 0) red[4 + wid] = lsum;
  __syncthreads();
  if (tid == 0) {
    float2 mi;
    mi.x = m;
    mi.y = 1.0f / (red[4] + red[5] + red[6] + red[7]);
    MI[blockIdx.x] = mi;
  }
}

// ---------------------------------------------------------------------------
// O = P @ V with softmax FUSED into A-staging: A-operand loaded to registers,
// p = (col<=qr) ? expf(v - m)*inv : 0, rounded to bf16, ds_write into the same
// XOR-swizzled LDS slots. Identical arithmetic to old softmax+store path.
// B (VT) stays on the global_load_lds DMA path, issued first so its latency
// hides under the exp VALU work. Causal K-trim; longest-first XCD mapping.
// ---------------------------------------------------------------------------
__global__ __launch_bounds__(256, 2)
void gemm_opv(const u16* __restrict__ P, int lda, long sA,
              const u16* __restrict__ VT, int ldb, long sB,
              float* __restrict__ C, int ldc, long sC,
              const float2* __restrict__ MI)
{
  int L = blockIdx.x;                        // 0..127
  int jj0 = L & 7, s = L >> 3;
  int by = (s < 8) ? 15 - jj0 : jj0;
  int bx = s & 7;
  int bz = blockIdx.y;
  int kmax = (by + 1) * TILE;

  __shared__ u16 As[TILE * BK];
  __shared__ u16 Bs[TILE * BK];

  const u16* Ab = P + bz * sA + (long)by * TILE * lda;
  const u16* Bb = VT + bz * sB + (long)bx * TILE * ldb;
  int tid = threadIdx.x;

  int lane = tid & 63;
  int wm = ((tid >> 7) & 1) * 64;
  int wn = ((tid >> 6) & 1) * 64;

  floatx4 acc[4][4] = {};
  int arow = wm + (lane & 15);
  int brow = wn + (lane & 15);
  int q = lane >> 4;

  // per-thread row stats: the 4 staged A-rows are fixed across the K-loop
  float mr[4], iv[4];
  int qr[4];
#pragma unroll
  for (int h = 0; h < 4; h++) {
    int cc = tid + h * 256;
    int row = cc >> 3;
    qr[h] = by * TILE + row;
    float2 mi = MI[bz * 2048 + qr[h]];
    mr[h] = mi.x; iv[h] = mi.y;
  }

  for (int k0 = 0; k0 < kmax; k0 += BK) {
    __syncthreads();
    // B: DMA path (issue first — latency hides under exp below)
#pragma unroll
    for (int h = 0; h < 4; h++) {
      int cc = tid + h * 256;
      int row = cc >> 3, gm = (cc & 7) ^ (row & 7);
      load16(Bb + (long)row * ldb + k0 + gm * 8, &Bs[cc * 8]);
    }
    // A: register-staged with fused softmax
#pragma unroll
    for (int h = 0; h < 4; h++) {
      int cc = tid + h * 256;
      int row = cc >> 3, gm = (cc & 7) ^ (row & 7);
      int c0 = k0 + gm * 8;
      u16x8 raw = *(const u16x8*)(Ab + (long)row * lda + c0);
      u16x8 ov;
#pragma unroll
      for (int j = 0; j < 8; j++) {
        float p = (c0 + j <= qr[h]) ? __expf(bf2f(raw[j]) - mr[h]) * iv[h] : 0.f;
        ov[j] = f2bf(p);
      }
      *(u16x8*)&As[cc * 8] = ov;
    }
    __builtin_amdgcn_s_waitcnt(0);
    __syncthreads();

#pragma unroll
    for (int kp = 0; kp < 2; kp++) {
      bf16x8 a[4], b[4];
#pragma unroll
      for (int i = 0; i < 4; i++) {
        int r = arow + i * 16;
        a[i] = *(const bf16x8*)&As[(r * 8 + ((kp * 4 + q) ^ (r & 7))) * 8];
      }
#pragma unroll
      for (int j = 0; j < 4; j++) {
        int r = brow + j * 16;
        b[j] = *(const bf16x8*)&Bs[(r * 8 + ((kp * 4 + q) ^ (r & 7))) * 8];
      }
#pragma unroll
      for (int i = 0; i < 4; i++)
#pragma unroll
        for (int j = 0; j < 4; j++)
          acc[i][j] = __builtin_amdgcn_mfma_f32_16x16x32_bf16(a[i], b[j], acc[i][j], 0, 0, 0);
    }
  }

  float* Cb = C + bz * sC;
  int colbase = bx * TILE + wn + (lane & 15);
  int rowbase = by * TILE + wm + ((lane >> 4) << 2);
#pragma unroll
  for (int i = 0; i < 4; i++)
#pragma unroll
    for (int j = 0; j < 4; j++) {
      int col = colbase + j * 16;
#pragma unroll
      for (int r = 0; r < 4; r++)
        Cb[(long)(rowbase + i * 16 + r) * ldc + col] = acc[i][j][r];
    }
}

// ---------------------------------------------------------------------------
// 256x256-tile, BK=64, 8-wave, 8-phase counted-vmcnt core (frozen since R2).
// ---------------------------------------------------------------------------
template<typename OutT>
__device__ __forceinline__ void gemm_core256(
    const u16* __restrict__ A, int lda, long sA,
    const u16* __restrict__ Bt, int ldb, long sB,
    OutT* __restrict__ C, int ldc, long sC,
    int kmax, int bx, int by, int bz, int tid, u16* lds)
{
  const u16* Ab = A + bz * sA + (long)by * 256 * lda;
  const u16* Bb = Bt + bz * sB + (long)bx * 256 * ldb;

  const int lane = tid & 63, wid = tid >> 6;
  const int wm = wid >> 2;
  const int wn = wid & 3;
  const int l15 = lane & 15, q = lane >> 4;

  const int cc0 = tid, cc1 = tid + 512;
  const int r0 = cc0 >> 3, g0 = (cc0 & 7) ^ (r0 & 7);
  const int r1 = cc1 >> 3, g1 = (cc1 & 7) ^ (r1 & 7);

  const int NK = kmax >> 6;

  floatx4 acc[8][4] = {};

  auto STAGE_A = [&](int k, int half, int buf) {
    const u16* g = Ab + (long)(half * 128) * lda + k * 64;
    load16(g + (long)r0 * lda + g0 * 8, lds + buf + half * 8192 + cc0 * 8);
    load16(g + (long)r1 * lda + g1 * 8, lds + buf + half * 8192 + cc1 * 8);
  };
  auto STAGE_B = [&](int k, int half, int buf) {
    const u16* g = Bb + (long)(half * 128) * ldb + k * 64;
    load16(g + (long)r0 * ldb + g0 * 8, lds + buf + 16384 + half * 8192 + cc0 * 8);
    load16(g + (long)r1 * ldb + g1 * 8, lds + buf + 16384 + half * 8192 + cc1 * 8);
  };

  STAGE_B(0, 0, 0); STAGE_B(0, 1, 0);
  STAGE_A(0, 0, 0); STAGE_A(0, 1, 0);
  if (NK > 1) {
    STAGE_B(1, 0, 32768); STAGE_B(1, 1, 32768);
    STAGE_A(1, 0, 32768);
    asm volatile("s_waitcnt vmcnt(6)" ::: "memory");
  } else {
    asm volatile("s_waitcnt vmcnt(0)" ::: "memory");
  }
  __builtin_amdgcn_s_barrier();

  const int s0 = (q ^ (l15 & 7)) * 8;
  const int s1 = ((q + 4) ^ (l15 & 7)) * 8;

  bf16x8 aL[2][4], aH[2][4], bL[2][2], bH[2][2];

  for (int t = 0; t < NK; ++t) {
    const int buf = (t & 1) ? 32768 : 0;
    const int nbuf = 32768 - buf;
    const int abase = buf + wm * 8192 + l15 * 64;
    const int bbase = buf + 16384 + (wn >> 1) * 8192 + ((wn & 1) * 64 + l15) * 64;

    // ---- P1
#pragma unroll
    for (int i = 0; i < 4; ++i) {
      aL[0][i] = *(const bf16x8*)&lds[abase + i * 1024 + s0];
      aL[1][i] = *(const bf16x8*)&lds[abase + i * 1024 + s1];
    }
#pragma unroll
    for (int j = 0; j < 2; ++j) {
      bL[0][j] = *(const bf16x8*)&lds[bbase + j * 1024 + s0];
      bL[1][j] = *(const bf16x8*)&lds[bbase + j * 1024 + s1];
    }
    if (t + 1 < NK) STAGE_A(t + 1, 1, nbuf);
    asm volatile("s_waitcnt lgkmcnt(8)" ::: "memory");
    __builtin_amdgcn_s_barrier();
    asm volatile("s_waitcnt lgkmcnt(0)" ::: "memory");
    __builtin_amdgcn_s_setprio(1);
#pragma unroll
    for (int kp = 0; kp < 2; ++kp)
#pragma unroll
      for (int i = 0; i < 4; ++i)
#pragma unroll
        for (int j = 0; j < 2; ++j)
          acc[i][j] = __builtin_amdgcn_mfma_f32_16x16x32_bf16(aL[kp][i], bL[kp][j], acc[i][j], 0, 0, 0);
    __builtin_amdgcn_s_setprio(0);
    asm volatile("" ::: "memory");
    __builtin_amdgcn_s_barrier();

    // ---- P2
#pragma unroll
    for (int j = 0; j < 2; ++j) {
      bH[0][j] = *(const bf16x8*)&lds[bbase + (2 + j) * 1024 + s0];
      bH[1][j] = *(const bf16x8*)&lds[bbase + (2 + j) * 1024 + s1];
    }
    asm volatile("" ::: "memory");
    __builtin_amdgcn_s_barrier();
    asm volatile("s_waitcnt lgkmcnt(0)" ::: "memory");
    __builtin_amdgcn_s_setprio(1);
#pragma unroll
    for (int kp = 0; kp < 2; ++kp)
#pragma unroll
      for (int i = 0; i < 4; ++i)
#pragma unroll
        for (int j = 0; j < 2; ++j)
          acc[i][2 + j] = __builtin_amdgcn_mfma_f32_16x16x32_bf16(aL[kp][i], bH[kp][j], acc[i][2 + j], 0, 0, 0);
    __builtin_amdgcn_s_setprio(0);
    asm volatile("" ::: "memory");
    __builtin_amdgcn_s_barrier();

    // ---- P3
#pragma unroll
    for (int i = 0; i < 4; ++i) {
      aH[0][i] = *(const bf16x8*)&lds[abase + 4096 + i * 1024 + s0];
      aH[1][i] = *(const bf16x8*)&lds[abase + 4096 + i * 1024 + s1];
    }
    if (t + 2 < NK) { STAGE_B(t + 2, 0, buf); STAGE_B(t + 2, 1, buf); }
    asm volatile("" ::: "memory");
    __builtin_amdgcn_s_barrier();
    asm volatile("s_waitcnt lgkmcnt(0)" ::: "memory");
    __builtin_amdgcn_s_setprio(1);
#pragma unroll
    for (int kp = 0; kp < 2; ++kp)
#pragma unroll
      for (int i = 0; i < 4; ++i)
#pragma unroll
        for (int j = 0; j < 2; ++j)
          acc[4 + i][2 + j] = __builtin_amdgcn_mfma_f32_16x16x32_bf16(aH[kp][i], bH[kp][j], acc[4 + i][2 + j], 0, 0, 0);
    __builtin_amdgcn_s_setprio(0);
    asm volatile("" ::: "memory");
    __builtin_amdgcn_s_barrier();

    // ---- P4
    if (t + 2 < NK) {
      STAGE_A(t + 2, 0, buf);
      asm volatile("s_waitcnt vmcnt(6)" ::: "memory");
    } else {
      asm volatile("s_waitcnt vmcnt(0)" ::: "memory");
    }
    __builtin_amdgcn_s_barrier();
    __builtin_amdgcn_s_setprio(1);
#pragma unroll
    for (int kp = 0; kp < 2; ++kp)
#pragma unroll
      for (int i = 0; i < 4; ++i)
#pragma unroll
        for (int j = 0; j < 2; ++j)
          acc[4 + i][j] = __builtin_amdgcn_mfma_f32_16x16x32_bf16(aH[kp][i], bL[kp][j], acc[4 + i][j], 0, 0, 0);
    __builtin_amdgcn_s_setprio(0);
    asm volatile("" ::: "memory");
    __builtin_amdgcn_s_barrier();
  }

  OutT* Cb = C + bz * sC;
  const int colbase = bx * 256 + wn * 64 + l15;
  const int rowbase = by * 256 + wm * 128 + (q << 2);
#pragma unroll
  for (int i = 0; i < 8; ++i)
#pragma unroll
    for (int j = 0; j < 4; ++j) {
      const int col = colbase + j * 16;
#pragma unroll
      for (int r = 0; r < 4; ++r)
        st_out(&Cb[(long)(rowbase + i * 16 + r) * ldc + col], acc[i][j][r]);
    }
}

// Merged projections on the 256^2 8-phase core.
__global__ __launch_bounds__(512, 2)
void gemm256_proj(const u16* __restrict__ xb, const u16* __restrict__ NT,
                  const u16* __restrict__ WvT, u16* __restrict__ Yb,
                  u16* __restrict__ VT)
{
  extern __shared__ u16 lds[];
  int L = blockIdx.x;                  // 0..511
  int t = ((L & 7) << 6) | (L >> 3);   // 64 contiguous tiles per XCD
  bool h = (t >= 256);
  int tt = h ? (t - 256) : t;
  int bx = h ? (tt & 63) : (tt & 3);
  int by = h ? (tt >> 6) : (tt >> 2);
  gemm_core256<u16>(h ? WvT : xb, 1024, 0L,
                    h ? xb : NT, 1024, 0L,
                    h ? VT : Yb, h ? 16384 : 1024, 0L,
                    1024, bx, by, 0, (int)threadIdx.x, lds);
}

// fp32 -> bf16 with scale, 4 elems/thread
__global__ __launch_bounds__(256)
void cvt_x(const float4* __restrict__ x, u16* __restrict__ o, int n4, float scale)
{
  int i = blockIdx.x * 256 + threadIdx.x;
  if (i >= n4) return;
  float4 v = x[i];
  ushort4 r;
  r.x = f2bf(v.x * scale); r.y = f2bf(v.y * scale);
  r.z = f2bf(v.z * scale); r.w = f2bf(v.w * scale);
  *(ushort4*)(o + (long)i * 4) = r;
}

// Wq (scaled 1/32) and Wk converts merged into one dispatch
__global__ __launch_bounds__(256)
void cvt_qk(const float4* __restrict__ Wq, const float4* __restrict__ Wk,
            u16* __restrict__ oq, u16* __restrict__ ok, int n4)
{
  int i = blockIdx.x * 256 + threadIdx.x;
  if (i < n4) {
    float4 v = Wq[i];
    ushort4 r;
    r.x = f2bf(v.x * 0.03125f); r.y = f2bf(v.y * 0.03125f);
    r.z = f2bf(v.z * 0.03125f); r.w = f2bf(v.w * 0.03125f);
    *(ushort4*)(oq + (long)i * 4) = r;
  } else if (i < 2 * n4) {
    int k = i - n4;
    float4 v = Wk[k];
    ushort4 r;
    r.x = f2bf(v.x); r.y = f2bf(v.y); r.z = f2bf(v.z); r.w = f2bf(v.w);
    *(ushort4*)(ok + (long)k * 4) = r;
  }
}

// W (d_in x d_out) fp32 -> W^T (d_out x d_in) bf16, LDS tiled
__global__ __launch_bounds__(256)
void cvt_w(const float* __restrict__ W, u16* __restrict__ O)
{
  const int D = 1024;
  __shared__ float t[64][65];
  int tid = threadIdx.x;
  int c = tid & 63, r = tid >> 6;
  int e0 = blockIdx.x * 64, d0 = blockIdx.y * 64;
  for (int rr = r; rr < 64; rr += 4)
    t[rr][c] = W[(long)(d0 + rr) * D + e0 + c];
  __syncthreads();
  for (int rr = r; rr < 64; rr += 4)
    O[(long)(e0 + rr) * D + d0 + c] = f2bf(t[c][rr]);
}

extern "C" void kernel_launch(void* const* d_in, const int* in_sizes, int n_in,
                              void* d_out, int out_size, void* d_ws, size_t ws_size,
                              hipStream_t stream)
{
  const int B = 8, T = 2048, D = 1024;
  const float* x  = (const float*)d_in[0];
  const float* Wq = (const float*)d_in[1];
  const float* Wk = (const float*)d_in[2];
  const float* Wv = (const float*)d_in[3];
  float* out = (float*)d_out;
  char* ws = (char*)d_ws;

  // layout (MB): xb 0-32 | WvT 32-34 | NT 34-36 (reused as MI table after proj)
  // | Yb 36-68 (Wqb@36,Wkb@38 dead after NT gemm) | VT 68-100 | S bf16 @100
  u16* xb  = (u16*)(ws);
  u16* WvT = (u16*)(ws + (32ul << 20));
  u16* NT  = (u16*)(ws + (34ul << 20));
  u16* Yb  = (u16*)(ws + (36ul << 20));
  u16* Wqb = Yb;                            // transient
  u16* Wkb = (u16*)(ws + (38ul << 20));     // transient
  u16* VT  = (u16*)(ws + (68ul << 20));
  u16* S   = (u16*)(ws + (100ul << 20));
  float2* MI = (float2*)(ws + (34ul << 20)); // NT region, dead after proj

  const size_t OFF_S = 100ul << 20;
  int NB = 8;
  while (NB > 1 && OFF_S + (size_t)NB * T * T * 2 > ws_size) NB >>= 1;

  // one-time: allow 128 KiB dynamic LDS for the 8-phase core
  static bool attr_done = false;
  if (!attr_done) {
    hipFuncSetAttribute(reinterpret_cast<const void*>(gemm256_proj),
                        hipFuncAttributeMaxDynamicSharedMemorySize, 131072);
    attr_done = true;
  }

  cvt_x<<<(B * T * D / 4 + 255) / 256, 256, 0, stream>>>((const float4*)x, xb, B * T * D / 4, 1.0f);
  cvt_qk<<<(2 * D * D / 4 + 255) / 256, 256, 0, stream>>>(
      (const float4*)Wq, (const float4*)Wk, Wqb, Wkb, D * D / 4);
  cvt_w<<<dim3(16, 16), 256, 0, stream>>>(Wv, WvT);

  // NT[d',d] = sum_e Wk[d',e] Wq'[d,e]   (scale folded into Wq')
  gemm_rect<u16><<<dim3(64, 1), 256, 0, stream>>>(
      Wkb, D, 0L, Wqb, D, 0L, NT, D, 0L, D, 3, 3);
  // Y = xb @ NT^T  and  VT = WvT @ xb^T  in one dispatch (256^2 8-phase core)
  gemm256_proj<<<dim3(512, 1), 512, 131072, stream>>>(xb, NT, WvT, Yb, VT);

  for (int b0 = 0; b0 < B; b0 += NB) {
    gemm_tri<<<dim3(136, NB), 256, 0, stream>>>(
        Yb + (long)b0 * T * D, D, (long)T * D,
        xb + (long)b0 * T * D, D, (long)T * D,
        S, T, (long)T * T, D);
    rowstat<<<NB * T, 256, 0, stream>>>(S, MI);
    gemm_opv<<<dim3(128, NB), 256, 0, stream>>>(
        S, T, (long)T * T,
        VT + (long)b0 * T, B * T, (long)T,
        out + (long)b0 * T * D, D, (long)T * D,
        MI);
  }
}

// Round 5
// 371.771 us; speedup vs baseline: 1.0816x; 1.0816x over previous
//
#include <hip/hip_runtime.h>

using u16 = unsigned short;
typedef __bf16 bf16x8 __attribute__((ext_vector_type(8)));
typedef unsigned short u16x8 __attribute__((ext_vector_type(8)));
typedef float floatx4 __attribute__((ext_vector_type(4)));

__device__ __forceinline__ u16 f2bf(float f) {
  union { float f; unsigned u; } c; c.f = f;
  unsigned u = c.u;
  u += 0x7fffu + ((u >> 16) & 1u);   // round-to-nearest-even
  return (u16)(u >> 16);
}
__device__ __forceinline__ float bf2f(u16 h) {
  union { unsigned u; float f; } c; c.u = ((unsigned)h) << 16; return c.f;
}

__device__ __forceinline__ void st_out(float* p, float v) { *p = v; }
__device__ __forceinline__ void st_out(u16* p, float v) { *p = f2bf(v); }

__device__ __forceinline__ void load16(const u16* g, u16* l) {
  __builtin_amdgcn_global_load_lds(
      (const __attribute__((address_space(1))) void*)g,
      (__attribute__((address_space(3))) void*)l, 16, 0, 0);
}

#define TILE 128
#define BK 64

// ---------------------------------------------------------------------------
// Legacy 128x128 tile GEMM core (m97-structure) — used by rect.
// LDS: row r's 8 16B-chunks XOR-permuted (slot = m ^ (r&7)) -> 0 bank conflicts.
// ---------------------------------------------------------------------------
template<typename OutT>
__device__ __forceinline__ void gemm_core(
    const u16* __restrict__ A, int lda, long sA,
    const u16* __restrict__ Bt, int ldb, long sB,
    OutT* __restrict__ C, int ldc, long sC,
    int kmax, int bx, int by, int bz, int tid)
{
  __shared__ u16 As[TILE * BK];
  __shared__ u16 Bs[TILE * BK];

  const u16* Ab = A + bz * sA + (long)by * TILE * lda;
  const u16* Bb = Bt + bz * sB + (long)bx * TILE * ldb;

  int lane = tid & 63;
  int wm = ((tid >> 7) & 1) * 64;
  int wn = ((tid >> 6) & 1) * 64;

  floatx4 acc[4][4] = {};
  int arow = wm + (lane & 15);
  int brow = wn + (lane & 15);
  int q = lane >> 4;

  for (int k0 = 0; k0 < kmax; k0 += BK) {
    __syncthreads();
#pragma unroll
    for (int h = 0; h < 4; h++) {
      int cc = tid + h * 256;
      int row = cc >> 3, gm = (cc & 7) ^ (row & 7);
      load16(Ab + (long)row * lda + k0 + gm * 8, &As[cc * 8]);
    }
#pragma unroll
    for (int h = 0; h < 4; h++) {
      int cc = tid + h * 256;
      int row = cc >> 3, gm = (cc & 7) ^ (row & 7);
      load16(Bb + (long)row * ldb + k0 + gm * 8, &Bs[cc * 8]);
    }
    __builtin_amdgcn_s_waitcnt(0);
    __syncthreads();

#pragma unroll
    for (int kp = 0; kp < 2; kp++) {
      bf16x8 a[4], b[4];
#pragma unroll
      for (int i = 0; i < 4; i++) {
        int r = arow + i * 16;
        a[i] = *(const bf16x8*)&As[(r * 8 + ((kp * 4 + q) ^ (r & 7))) * 8];
      }
#pragma unroll
      for (int j = 0; j < 4; j++) {
        int r = brow + j * 16;
        b[j] = *(const bf16x8*)&Bs[(r * 8 + ((kp * 4 + q) ^ (r & 7))) * 8];
      }
#pragma unroll
      for (int i = 0; i < 4; i++)
#pragma unroll
        for (int j = 0; j < 4; j++)
          acc[i][j] = __builtin_amdgcn_mfma_f32_16x16x32_bf16(a[i], b[j], acc[i][j], 0, 0, 0);
    }
  }

  // epilogue: C/D layout col=lane&15, row=(lane>>4)*4+reg  [m89-verified]
  OutT* Cb = C + bz * sC;
  int colbase = bx * TILE + wn + (lane & 15);
  int rowbase = by * TILE + wm + ((lane >> 4) << 2);
#pragma unroll
  for (int i = 0; i < 4; i++)
#pragma unroll
    for (int j = 0; j < 4; j++) {
      int col = colbase + j * 16;
#pragma unroll
      for (int r = 0; r < 4; r++)
        st_out(&Cb[(long)(rowbase + i * 16 + r) * ldc + col], acc[i][j][r]);
    }
}

// Small rectangular GEMM (used for NT), XCD-contiguous remap
template<typename OutT>
__global__ __launch_bounds__(256, 2)
void gemm_rect(const u16* __restrict__ A, int lda, long sA,
               const u16* __restrict__ Bt, int ldb, long sB,
               OutT* __restrict__ C, int ldc, long sC, int K,
               int l2gx, int nO8s)
{
  int L = blockIdx.x;
  int t = ((L & 7) << nO8s) | (L >> 3);
  int bx = t & ((1 << l2gx) - 1), by = t >> l2gx;
  gemm_core<OutT>(A, lda, sA, Bt, ldb, sB, C, ldc, sC, K, bx, by, blockIdx.y, threadIdx.x);
}

// ---------------------------------------------------------------------------
// WIDENED 128x256 core (R5): 4 waves, each owns the full 128 M-rows x 64 N-cols
// (8 i-frags x 4 j-frags, acc[8][4]) -> 24 ds_read_b128 per 64 MFMA per wave
// per K-step (1:2.67 vs legacy 1:2). LDS 48 KB -> 2 blocks/CU kept: cross-block
// overlap hides the barrier drain (the m97 structure's saving grace), while the
// better read:MFMA ratio raises the LDS-pipe ceiling. Same XOR-chunk swizzle.
// ---------------------------------------------------------------------------
template<typename OutT>
__device__ __forceinline__ void gemm_core_w(
    const u16* __restrict__ A, int lda, long sA,
    const u16* __restrict__ Bt, int ldb, long sB,
    OutT* __restrict__ C, int ldc, long sC,
    int kmax, int bx, int by, int bz, int tid)   // bx counts 256-col tiles
{
  __shared__ u16 As[128 * BK];     // 16 KB
  __shared__ u16 Bs[256 * BK];     // 32 KB

  const u16* Ab = A + bz * sA + (long)by * 128 * lda;
  const u16* Bb = Bt + bz * sB + (long)bx * 256 * ldb;

  int lane = tid & 63;
  int wid = tid >> 6;              // 0..3 = N-quadrant (64 cols each)
  int l15 = lane & 15, q = lane >> 4;

  floatx4 acc[8][4] = {};

  for (int k0 = 0; k0 < kmax; k0 += BK) {
    __syncthreads();
#pragma unroll
    for (int h = 0; h < 4; h++) {              // A: 1024 16B-chunks
      int cc = tid + h * 256;
      int row = cc >> 3, gm = (cc & 7) ^ (row & 7);
      load16(Ab + (long)row * lda + k0 + gm * 8, &As[cc * 8]);
    }
#pragma unroll
    for (int h = 0; h < 8; h++) {              // B: 2048 16B-chunks
      int cc = tid + h * 256;
      int row = cc >> 3, gm = (cc & 7) ^ (row & 7);
      load16(Bb + (long)row * ldb + k0 + gm * 8, &Bs[cc * 8]);
    }
    __builtin_amdgcn_s_waitcnt(0);
    __syncthreads();

#pragma unroll
    for (int kp = 0; kp < 2; kp++) {
      bf16x8 a[8], b[4];
#pragma unroll
      for (int i = 0; i < 8; i++) {
        int r = l15 + i * 16;
        a[i] = *(const bf16x8*)&As[(r * 8 + ((kp * 4 + q) ^ (r & 7))) * 8];
      }
#pragma unroll
      for (int j = 0; j < 4; j++) {
        int r = wid * 64 + l15 + j * 16;
        b[j] = *(const bf16x8*)&Bs[(r * 8 + ((kp * 4 + q) ^ (r & 7))) * 8];
      }
#pragma unroll
      for (int i = 0; i < 8; i++)
#pragma unroll
        for (int j = 0; j < 4; j++)
          acc[i][j] = __builtin_amdgcn_mfma_f32_16x16x32_bf16(a[i], b[j], acc[i][j], 0, 0, 0);
    }
  }

  OutT* Cb = C + bz * sC;
  int colbase = bx * 256 + wid * 64 + l15;
  int rowbase = by * 128 + (q << 2);
#pragma unroll
  for (int i = 0; i < 8; i++)
#pragma unroll
    for (int j = 0; j < 4; j++) {
      int col = colbase + j * 16;
#pragma unroll
      for (int r = 0; r < 4; r++)
        st_out(&Cb[(long)(rowbase + i * 16 + r) * ldc + col], acc[i][j][r]);
    }
}

// Causal S = Y @ x^T -> bf16 scores (scale pre-folded into Wq), widened core.
// 72 column-PAIR tiles per batch: (r, cp) with 2cp <= r. When 2cp+1 > r the
// partner tile is computed from valid memory but is garbage — provably never
// read: softmax trims to W=(r+1)*128 and opv trims K to (by+1)*128.
// XCD j gets t = j*9..j*9+8 (contiguous triangle slots, A-strip locality).
__global__ __launch_bounds__(256, 2)
void gemm_tri(const u16* __restrict__ A, int lda, long sA,
              const u16* __restrict__ Bt, int ldb, long sB,
              u16* __restrict__ C, int ldc, long sC, int K)
{
  int tp = blockIdx.x;                 // 0..71
  int t = (tp & 7) * 9 + (tp >> 3);    // 9 contiguous slots per XCD
  int r = 0, pre = 0;
  while (pre + (r / 2 + 1) <= t) { pre += r / 2 + 1; ++r; }
  int cp = t - pre;
  gemm_core_w<u16>(A, lda, sA, Bt, ldb, sB, C, ldc, sC, K, cp, r, blockIdx.y, threadIdx.x);
}

// O = P @ V via VT, widened core (128 q-rows x 256 e-cols per block).
// 64 blocks/batch x 8 batches = 512 = exactly one 2-blocks/CU round; each XCD
// pairs a long strip (by=15-j) with a short one (by=j) for K-balance.
__global__ __launch_bounds__(256, 2)
void gemm_opv(const u16* __restrict__ P, int lda, long sA,
              const u16* __restrict__ VT, int ldb, long sB,
              float* __restrict__ C, int ldc, long sC)
{
  int L = blockIdx.x;                  // 0..63
  int j = L & 7, s = L >> 3;
  int by = (s < 4) ? 15 - j : j;
  int bxp = s & 3;
  gemm_core_w<float>(P, lda, sA, VT, ldb, sB, C, ldc, sC,
                     (by + 1) * TILE, bxp, by, blockIdx.y, threadIdx.x);
}

// ---------------------------------------------------------------------------
// 256x256-tile, BK=64, 8-wave, 8-phase counted-vmcnt core (frozen since R2).
// ---------------------------------------------------------------------------
template<typename OutT>
__device__ __forceinline__ void gemm_core256(
    const u16* __restrict__ A, int lda, long sA,
    const u16* __restrict__ Bt, int ldb, long sB,
    OutT* __restrict__ C, int ldc, long sC,
    int kmax, int bx, int by, int bz, int tid, u16* lds)
{
  const u16* Ab = A + bz * sA + (long)by * 256 * lda;
  const u16* Bb = Bt + bz * sB + (long)bx * 256 * ldb;

  const int lane = tid & 63, wid = tid >> 6;
  const int wm = wid >> 2;
  const int wn = wid & 3;
  const int l15 = lane & 15, q = lane >> 4;

  const int cc0 = tid, cc1 = tid + 512;
  const int r0 = cc0 >> 3, g0 = (cc0 & 7) ^ (r0 & 7);
  const int r1 = cc1 >> 3, g1 = (cc1 & 7) ^ (r1 & 7);

  const int NK = kmax >> 6;

  floatx4 acc[8][4] = {};

  auto STAGE_A = [&](int k, int half, int buf) {
    const u16* g = Ab + (long)(half * 128) * lda + k * 64;
    load16(g + (long)r0 * lda + g0 * 8, lds + buf + half * 8192 + cc0 * 8);
    load16(g + (long)r1 * lda + g1 * 8, lds + buf + half * 8192 + cc1 * 8);
  };
  auto STAGE_B = [&](int k, int half, int buf) {
    const u16* g = Bb + (long)(half * 128) * ldb + k * 64;
    load16(g + (long)r0 * ldb + g0 * 8, lds + buf + 16384 + half * 8192 + cc0 * 8);
    load16(g + (long)r1 * ldb + g1 * 8, lds + buf + 16384 + half * 8192 + cc1 * 8);
  };

  STAGE_B(0, 0, 0); STAGE_B(0, 1, 0);
  STAGE_A(0, 0, 0); STAGE_A(0, 1, 0);
  if (NK > 1) {
    STAGE_B(1, 0, 32768); STAGE_B(1, 1, 32768);
    STAGE_A(1, 0, 32768);
    asm volatile("s_waitcnt vmcnt(6)" ::: "memory");
  } else {
    asm volatile("s_waitcnt vmcnt(0)" ::: "memory");
  }
  __builtin_amdgcn_s_barrier();

  const int s0 = (q ^ (l15 & 7)) * 8;
  const int s1 = ((q + 4) ^ (l15 & 7)) * 8;

  bf16x8 aL[2][4], aH[2][4], bL[2][2], bH[2][2];

  for (int t = 0; t < NK; ++t) {
    const int buf = (t & 1) ? 32768 : 0;
    const int nbuf = 32768 - buf;
    const int abase = buf + wm * 8192 + l15 * 64;
    const int bbase = buf + 16384 + (wn >> 1) * 8192 + ((wn & 1) * 64 + l15) * 64;

    // ---- P1
#pragma unroll
    for (int i = 0; i < 4; ++i) {
      aL[0][i] = *(const bf16x8*)&lds[abase + i * 1024 + s0];
      aL[1][i] = *(const bf16x8*)&lds[abase + i * 1024 + s1];
    }
#pragma unroll
    for (int j = 0; j < 2; ++j) {
      bL[0][j] = *(const bf16x8*)&lds[bbase + j * 1024 + s0];
      bL[1][j] = *(const bf16x8*)&lds[bbase + j * 1024 + s1];
    }
    if (t + 1 < NK) STAGE_A(t + 1, 1, nbuf);
    asm volatile("s_waitcnt lgkmcnt(8)" ::: "memory");
    __builtin_amdgcn_s_barrier();
    asm volatile("s_waitcnt lgkmcnt(0)" ::: "memory");
    __builtin_amdgcn_s_setprio(1);
#pragma unroll
    for (int kp = 0; kp < 2; ++kp)
#pragma unroll
      for (int i = 0; i < 4; ++i)
#pragma unroll
        for (int j = 0; j < 2; ++j)
          acc[i][j] = __builtin_amdgcn_mfma_f32_16x16x32_bf16(aL[kp][i], bL[kp][j], acc[i][j], 0, 0, 0);
    __builtin_amdgcn_s_setprio(0);
    asm volatile("" ::: "memory");
    __builtin_amdgcn_s_barrier();

    // ---- P2
#pragma unroll
    for (int j = 0; j < 2; ++j) {
      bH[0][j] = *(const bf16x8*)&lds[bbase + (2 + j) * 1024 + s0];
      bH[1][j] = *(const bf16x8*)&lds[bbase + (2 + j) * 1024 + s1];
    }
    asm volatile("" ::: "memory");
    __builtin_amdgcn_s_barrier();
    asm volatile("s_waitcnt lgkmcnt(0)" ::: "memory");
    __builtin_amdgcn_s_setprio(1);
#pragma unroll
    for (int kp = 0; kp < 2; ++kp)
#pragma unroll
      for (int i = 0; i < 4; ++i)
#pragma unroll
        for (int j = 0; j < 2; ++j)
          acc[i][2 + j] = __builtin_amdgcn_mfma_f32_16x16x32_bf16(aL[kp][i], bH[kp][j], acc[i][2 + j], 0, 0, 0);
    __builtin_amdgcn_s_setprio(0);
    asm volatile("" ::: "memory");
    __builtin_amdgcn_s_barrier();

    // ---- P3
#pragma unroll
    for (int i = 0; i < 4; ++i) {
      aH[0][i] = *(const bf16x8*)&lds[abase + 4096 + i * 1024 + s0];
      aH[1][i] = *(const bf16x8*)&lds[abase + 4096 + i * 1024 + s1];
    }
    if (t + 2 < NK) { STAGE_B(t + 2, 0, buf); STAGE_B(t + 2, 1, buf); }
    asm volatile("" ::: "memory");
    __builtin_amdgcn_s_barrier();
    asm volatile("s_waitcnt lgkmcnt(0)" ::: "memory");
    __builtin_amdgcn_s_setprio(1);
#pragma unroll
    for (int kp = 0; kp < 2; ++kp)
#pragma unroll
      for (int i = 0; i < 4; ++i)
#pragma unroll
        for (int j = 0; j < 2; ++j)
          acc[4 + i][2 + j] = __builtin_amdgcn_mfma_f32_16x16x32_bf16(aH[kp][i], bH[kp][j], acc[4 + i][2 + j], 0, 0, 0);
    __builtin_amdgcn_s_setprio(0);
    asm volatile("" ::: "memory");
    __builtin_amdgcn_s_barrier();

    // ---- P4
    if (t + 2 < NK) {
      STAGE_A(t + 2, 0, buf);
      asm volatile("s_waitcnt vmcnt(6)" ::: "memory");
    } else {
      asm volatile("s_waitcnt vmcnt(0)" ::: "memory");
    }
    __builtin_amdgcn_s_barrier();
    __builtin_amdgcn_s_setprio(1);
#pragma unroll
    for (int kp = 0; kp < 2; ++kp)
#pragma unroll
      for (int i = 0; i < 4; ++i)
#pragma unroll
        for (int j = 0; j < 2; ++j)
          acc[4 + i][j] = __builtin_amdgcn_mfma_f32_16x16x32_bf16(aH[kp][i], bL[kp][j], acc[4 + i][j], 0, 0, 0);
    __builtin_amdgcn_s_setprio(0);
    asm volatile("" ::: "memory");
    __builtin_amdgcn_s_barrier();
  }

  OutT* Cb = C + bz * sC;
  const int colbase = bx * 256 + wn * 64 + l15;
  const int rowbase = by * 256 + wm * 128 + (q << 2);
#pragma unroll
  for (int i = 0; i < 8; ++i)
#pragma unroll
    for (int j = 0; j < 4; ++j) {
      const int col = colbase + j * 16;
#pragma unroll
      for (int r = 0; r < 4; ++r)
        st_out(&Cb[(long)(rowbase + i * 16 + r) * ldc + col], acc[i][j][r]);
    }
}

// Merged projections on the 256^2 8-phase core.
__global__ __launch_bounds__(512, 2)
void gemm256_proj(const u16* __restrict__ xb, const u16* __restrict__ NT,
                  const u16* __restrict__ WvT, u16* __restrict__ Yb,
                  u16* __restrict__ VT)
{
  extern __shared__ u16 lds[];
  int L = blockIdx.x;                  // 0..511
  int t = ((L & 7) << 6) | (L >> 3);   // 64 contiguous tiles per XCD
  bool h = (t >= 256);
  int tt = h ? (t - 256) : t;
  int bx = h ? (tt & 63) : (tt & 3);
  int by = h ? (tt >> 6) : (tt >> 2);
  gemm_core256<u16>(h ? WvT : xb, 1024, 0L,
                    h ? xb : NT, 1024, 0L,
                    h ? VT : Yb, h ? 16384 : 1024, 0L,
                    1024, bx, by, 0, (int)threadIdx.x, lds);
}

// fp32 -> bf16 with scale, 4 elems/thread
__global__ __launch_bounds__(256)
void cvt_x(const float4* __restrict__ x, u16* __restrict__ o, int n4, float scale)
{
  int i = blockIdx.x * 256 + threadIdx.x;
  if (i >= n4) return;
  float4 v = x[i];
  ushort4 r;
  r.x = f2bf(v.x * scale); r.y = f2bf(v.y * scale);
  r.z = f2bf(v.z * scale); r.w = f2bf(v.w * scale);
  *(ushort4*)(o + (long)i * 4) = r;
}

// Wq (scaled 1/32) and Wk converts merged into one dispatch
__global__ __launch_bounds__(256)
void cvt_qk(const float4* __restrict__ Wq, const float4* __restrict__ Wk,
            u16* __restrict__ oq, u16* __restrict__ ok, int n4)
{
  int i = blockIdx.x * 256 + threadIdx.x;
  if (i < n4) {
    float4 v = Wq[i];
    ushort4 r;
    r.x = f2bf(v.x * 0.03125f); r.y = f2bf(v.y * 0.03125f);
    r.z = f2bf(v.z * 0.03125f); r.w = f2bf(v.w * 0.03125f);
    *(ushort4*)(oq + (long)i * 4) = r;
  } else if (i < 2 * n4) {
    int k = i - n4;
    float4 v = Wk[k];
    ushort4 r;
    r.x = f2bf(v.x); r.y = f2bf(v.y); r.z = f2bf(v.z); r.w = f2bf(v.w);
    *(ushort4*)(ok + (long)k * 4) = r;
  }
}

// W (d_in x d_out) fp32 -> W^T (d_out x d_in) bf16, LDS tiled
__global__ __launch_bounds__(256)
void cvt_w(const float* __restrict__ W, u16* __restrict__ O)
{
  const int D = 1024;
  __shared__ float t[64][65];
  int tid = threadIdx.x;
  int c = tid & 63, r = tid >> 6;
  int e0 = blockIdx.x * 64, d0 = blockIdx.y * 64;
  for (int rr = r; rr < 64; rr += 4)
    t[rr][c] = W[(long)(d0 + rr) * D + e0 + c];
  __syncthreads();
  for (int rr = r; rr < 64; rr += 4)
    O[(long)(e0 + rr) * D + d0 + c] = f2bf(t[c][rr]);
}

// causal softmax over bf16 scores, in-place; one block per row, 8 elems/thread.
// Causal trim (R3): threads with i0 >= W = ((row>>7)+1)*128 skip load+store
// (still join barriers/shuffles); [n, W) written as zeros (opv reads it).
__global__ __launch_bounds__(256)
void softmax_bf16(u16* __restrict__ S)
{
  const int T = 2048;
  int row = blockIdx.x & (T - 1);
  u16* Prow = S + (long)blockIdx.x * T;    // (bi*T+row)*T
  int n = row + 1;
  int W = ((row >> 7) + 1) << 7;           // cols opv will read
  int tid = threadIdx.x, lane = tid & 63, wid = tid >> 6;
  int i0 = tid * 8;
  bool act = (i0 < W);

  float v[8];
  float lmax = -3.0e38f;
  if (act) {
    u16x8 pv = *(const u16x8*)(Prow + i0);
#pragma unroll
    for (int j = 0; j < 8; j++) {
      v[j] = (i0 + j < n) ? bf2f(pv[j]) : -3.0e38f;
      lmax = fmaxf(lmax, v[j]);
    }
  }
  __shared__ float red[8];
#pragma unroll
  for (int o = 32; o > 0; o >>= 1) lmax = fmaxf(lmax, __shfl_down(lmax, o, 64));
  if (lane == 0) red[wid] = lmax;
  __syncthreads();
  float m = fmaxf(fmaxf(red[0], red[1]), fmaxf(red[2], red[3]));

  float lsum = 0.f;
  if (act) {
#pragma unroll
    for (int j = 0; j < 8; j++) {
      float e = (i0 + j < n) ? __expf(v[j] - m) : 0.f;
      v[j] = e;
      lsum += e;
    }
  }
#pragma unroll
  for (int o = 32; o > 0; o >>= 1) lsum += __shfl_down(lsum, o, 64);
  if (lane == 0) red[4 + wid] = lsum;
  __syncthreads();
  float inv = 1.0f / (red[4] + red[5] + red[6] + red[7]);

  if (act) {
    u16x8 w;
#pragma unroll
    for (int j = 0; j < 8; j++) w[j] = f2bf(v[j] * inv);
    *(u16x8*)(Prow + i0) = w;
  }
}

extern "C" void kernel_launch(void* const* d_in, const int* in_sizes, int n_in,
                              void* d_out, int out_size, void* d_ws, size_t ws_size,
                              hipStream_t stream)
{
  const int B = 8, T = 2048, D = 1024;
  const float* x  = (const float*)d_in[0];
  const float* Wq = (const float*)d_in[1];
  const float* Wk = (const float*)d_in[2];
  const float* Wv = (const float*)d_in[3];
  float* out = (float*)d_out;
  char* ws = (char*)d_ws;

  // layout (MB): xb 0-32 | WvT 32-34 | NT 34-36 | Yb 36-68 (Wqb@36,Wkb@38 dead
  // after NT gemm) | VT 68-100 | S bf16 @100 (8 MB/batch)
  u16* xb  = (u16*)(ws);
  u16* WvT = (u16*)(ws + (32ul << 20));
  u16* NT  = (u16*)(ws + (34ul << 20));
  u16* Yb  = (u16*)(ws + (36ul << 20));
  u16* Wqb = Yb;                            // transient
  u16* Wkb = (u16*)(ws + (38ul << 20));     // transient
  u16* VT  = (u16*)(ws + (68ul << 20));
  u16* S   = (u16*)(ws + (100ul << 20));

  const size_t OFF_S = 100ul << 20;
  int NB = 8;
  while (NB > 1 && OFF_S + (size_t)NB * T * T * 2 > ws_size) NB >>= 1;

  // one-time: allow 128 KiB dynamic LDS for the 8-phase core
  static bool attr_done = false;
  if (!attr_done) {
    hipFuncSetAttribute(reinterpret_cast<const void*>(gemm256_proj),
                        hipFuncAttributeMaxDynamicSharedMemorySize, 131072);
    attr_done = true;
  }

  cvt_x<<<(B * T * D / 4 + 255) / 256, 256, 0, stream>>>((const float4*)x, xb, B * T * D / 4, 1.0f);
  cvt_qk<<<(2 * D * D / 4 + 255) / 256, 256, 0, stream>>>(
      (const float4*)Wq, (const float4*)Wk, Wqb, Wkb, D * D / 4);
  cvt_w<<<dim3(16, 16), 256, 0, stream>>>(Wv, WvT);

  // NT[d',d] = sum_e Wk[d',e] Wq'[d,e]   (scale folded into Wq')
  gemm_rect<u16><<<dim3(64, 1), 256, 0, stream>>>(
      Wkb, D, 0L, Wqb, D, 0L, NT, D, 0L, D, 3, 3);
  // Y = xb @ NT^T  and  VT = WvT @ xb^T  in one dispatch (256^2 8-phase core)
  gemm256_proj<<<dim3(512, 1), 512, 131072, stream>>>(xb, NT, WvT, Yb, VT);

  for (int b0 = 0; b0 < B; b0 += NB) {
    gemm_tri<<<dim3(72, NB), 256, 0, stream>>>(
        Yb + (long)b0 * T * D, D, (long)T * D,
        xb + (long)b0 * T * D, D, (long)T * D,
        S, T, (long)T * T, D);
    softmax_bf16<<<NB * T, 256, 0, stream>>>(S);
    gemm_opv<<<dim3(64, NB), 256, 0, stream>>>(
        S, T, (long)T * T,
        VT + (long)b0 * T, B * T, (long)T,
        out + (long)b0 * T * D, D, (long)T * D);
  }
}

// Round 6
// 367.037 us; speedup vs baseline: 1.0956x; 1.0129x over previous
//
#include <hip/hip_runtime.h>

using u16 = unsigned short;
typedef __bf16 bf16x8 __attribute__((ext_vector_type(8)));
typedef unsigned short u16x8 __attribute__((ext_vector_type(8)));
typedef float floatx4 __attribute__((ext_vector_type(4)));

__device__ __forceinline__ u16 f2bf(float f) {
  union { float f; unsigned u; } c; c.f = f;
  unsigned u = c.u;
  u += 0x7fffu + ((u >> 16) & 1u);   // round-to-nearest-even
  return (u16)(u >> 16);
}
__device__ __forceinline__ float bf2f(u16 h) {
  union { unsigned u; float f; } c; c.u = ((unsigned)h) << 16; return c.f;
}

__device__ __forceinline__ void st_out(float* p, float v) { *p = v; }
__device__ __forceinline__ void st_out(u16* p, float v) { *p = f2bf(v); }

__device__ __forceinline__ void load16(const u16* g, u16* l) {
  __builtin_amdgcn_global_load_lds(
      (const __attribute__((address_space(1))) void*)g,
      (__attribute__((address_space(3))) void*)l, 16, 0, 0);
}

#define TILE 128
#define BK 64

// ---------------------------------------------------------------------------
// Legacy 128x128 tile GEMM core (m97-structure) — used by rect/tri/opv.
// LDS: row r's 8 16B-chunks XOR-permuted (slot = m ^ (r&7)) -> 0 bank conflicts.
// VGPR 68 / LDS 32KB: grid size is the occupancy limiter, so tri/opv use
// 128^2 tiles (1088/1024 blocks = ~4 blocks/CU co-resident).
// ---------------------------------------------------------------------------
template<typename OutT>
__device__ __forceinline__ void gemm_core(
    const u16* __restrict__ A, int lda, long sA,
    const u16* __restrict__ Bt, int ldb, long sB,
    OutT* __restrict__ C, int ldc, long sC,
    int kmax, int bx, int by, int bz, int tid)
{
  __shared__ u16 As[TILE * BK];
  __shared__ u16 Bs[TILE * BK];

  const u16* Ab = A + bz * sA + (long)by * TILE * lda;
  const u16* Bb = Bt + bz * sB + (long)bx * TILE * ldb;

  int lane = tid & 63;
  int wm = ((tid >> 7) & 1) * 64;
  int wn = ((tid >> 6) & 1) * 64;

  floatx4 acc[4][4] = {};
  int arow = wm + (lane & 15);
  int brow = wn + (lane & 15);
  int q = lane >> 4;

  for (int k0 = 0; k0 < kmax; k0 += BK) {
    __syncthreads();
#pragma unroll
    for (int h = 0; h < 4; h++) {
      int cc = tid + h * 256;
      int row = cc >> 3, gm = (cc & 7) ^ (row & 7);
      load16(Ab + (long)row * lda + k0 + gm * 8, &As[cc * 8]);
    }
#pragma unroll
    for (int h = 0; h < 4; h++) {
      int cc = tid + h * 256;
      int row = cc >> 3, gm = (cc & 7) ^ (row & 7);
      load16(Bb + (long)row * ldb + k0 + gm * 8, &Bs[cc * 8]);
    }
    __builtin_amdgcn_s_waitcnt(0);
    __syncthreads();

#pragma unroll
    for (int kp = 0; kp < 2; kp++) {
      bf16x8 a[4], b[4];
#pragma unroll
      for (int i = 0; i < 4; i++) {
        int r = arow + i * 16;
        a[i] = *(const bf16x8*)&As[(r * 8 + ((kp * 4 + q) ^ (r & 7))) * 8];
      }
#pragma unroll
      for (int j = 0; j < 4; j++) {
        int r = brow + j * 16;
        b[j] = *(const bf16x8*)&Bs[(r * 8 + ((kp * 4 + q) ^ (r & 7))) * 8];
      }
#pragma unroll
      for (int i = 0; i < 4; i++)
#pragma unroll
        for (int j = 0; j < 4; j++)
          acc[i][j] = __builtin_amdgcn_mfma_f32_16x16x32_bf16(a[i], b[j], acc[i][j], 0, 0, 0);
    }
  }

  // epilogue: C/D layout col=lane&15, row=(lane>>4)*4+reg  [m89-verified]
  OutT* Cb = C + bz * sC;
  int colbase = bx * TILE + wn + (lane & 15);
  int rowbase = by * TILE + wm + ((lane >> 4) << 2);
#pragma unroll
  for (int i = 0; i < 4; i++)
#pragma unroll
    for (int j = 0; j < 4; j++) {
      int col = colbase + j * 16;
#pragma unroll
      for (int r = 0; r < 4; r++)
        st_out(&Cb[(long)(rowbase + i * 16 + r) * ldc + col], acc[i][j][r]);
    }
}

// Small rectangular GEMM (used for NT), XCD-contiguous remap
template<typename OutT>
__global__ __launch_bounds__(256, 2)
void gemm_rect(const u16* __restrict__ A, int lda, long sA,
               const u16* __restrict__ Bt, int ldb, long sB,
               OutT* __restrict__ C, int ldc, long sC, int K,
               int l2gx, int nO8s)
{
  int L = blockIdx.x;
  int t = ((L & 7) << nO8s) | (L >> 3);
  int bx = t & ((1 << l2gx) - 1), by = t >> l2gx;
  gemm_core<OutT>(A, lda, sA, Bt, ldb, sB, C, ldc, sC, K, bx, by, blockIdx.y, threadIdx.x);
}

// Causal S = Y @ x^T -> bf16 scores (scale pre-folded into Wq). 136 tiles/batch.
// 2x2 super-block triangle walk (R3-best): per-XCD working set ~1 MB (L2-fit).
__global__ __launch_bounds__(256, 2)
void gemm_tri(const u16* __restrict__ A, int lda, long sA,
              const u16* __restrict__ Bt, int ldb, long sB,
              u16* __restrict__ C, int ldc, long sC, int K)
{
  int tp = blockIdx.x;                       // 0..135
  int g = (tp & 7) * 17 + (tp >> 3);         // 17 contiguous slots per XCD
  int sr = 0, sc = 0, pre = 0;
  for (;;) {
    int sz = (sr == sc) ? 3 : 4;
    if (pre + sz > g) break;
    pre += sz; ++sc;
    if (sc > sr) { ++sr; sc = 0; }
  }
  int w = g - pre;
  int r, c;
  if (sr == sc) { r = 2 * sr + (w > 0); c = 2 * sc + (w == 2); }
  else          { r = 2 * sr + (w >> 1); c = 2 * sc + (w & 1); }
  gemm_core<u16>(A, lda, sA, Bt, ldb, sB, C, ldc, sC, K, c, r, blockIdx.y, threadIdx.x);
}

// O = P @ V via VT; causal K-trim. XCD j runs long row (15-j) FIRST, then row j
// (longest-first: short blocks fill the tail). 1024 blocks = 4/CU.
__global__ __launch_bounds__(256, 2)
void gemm_opv(const u16* __restrict__ P, int lda, long sA,
              const u16* __restrict__ VT, int ldb, long sB,
              float* __restrict__ C, int ldc, long sC)
{
  int L = blockIdx.x;                        // 0..127
  int j = L & 7, s = L >> 3;
  int by = (s < 8) ? 15 - j : j;
  int bx = s & 7;
  gemm_core<float>(P, lda, sA, VT, ldb, sB, C, ldc, sC,
                   (by + 1) * TILE, bx, by, blockIdx.y, threadIdx.x);
}

// ---------------------------------------------------------------------------
// 256x256-tile, BK=64, 8-wave, 8-phase counted-vmcnt core (frozen since R2).
// ---------------------------------------------------------------------------
template<typename OutT>
__device__ __forceinline__ void gemm_core256(
    const u16* __restrict__ A, int lda, long sA,
    const u16* __restrict__ Bt, int ldb, long sB,
    OutT* __restrict__ C, int ldc, long sC,
    int kmax, int bx, int by, int bz, int tid, u16* lds)
{
  const u16* Ab = A + bz * sA + (long)by * 256 * lda;
  const u16* Bb = Bt + bz * sB + (long)bx * 256 * ldb;

  const int lane = tid & 63, wid = tid >> 6;
  const int wm = wid >> 2;
  const int wn = wid & 3;
  const int l15 = lane & 15, q = lane >> 4;

  const int cc0 = tid, cc1 = tid + 512;
  const int r0 = cc0 >> 3, g0 = (cc0 & 7) ^ (r0 & 7);
  const int r1 = cc1 >> 3, g1 = (cc1 & 7) ^ (r1 & 7);

  const int NK = kmax >> 6;

  floatx4 acc[8][4] = {};

  auto STAGE_A = [&](int k, int half, int buf) {
    const u16* g = Ab + (long)(half * 128) * lda + k * 64;
    load16(g + (long)r0 * lda + g0 * 8, lds + buf + half * 8192 + cc0 * 8);
    load16(g + (long)r1 * lda + g1 * 8, lds + buf + half * 8192 + cc1 * 8);
  };
  auto STAGE_B = [&](int k, int half, int buf) {
    const u16* g = Bb + (long)(half * 128) * ldb + k * 64;
    load16(g + (long)r0 * ldb + g0 * 8, lds + buf + 16384 + half * 8192 + cc0 * 8);
    load16(g + (long)r1 * ldb + g1 * 8, lds + buf + 16384 + half * 8192 + cc1 * 8);
  };

  STAGE_B(0, 0, 0); STAGE_B(0, 1, 0);
  STAGE_A(0, 0, 0); STAGE_A(0, 1, 0);
  if (NK > 1) {
    STAGE_B(1, 0, 32768); STAGE_B(1, 1, 32768);
    STAGE_A(1, 0, 32768);
    asm volatile("s_waitcnt vmcnt(6)" ::: "memory");
  } else {
    asm volatile("s_waitcnt vmcnt(0)" ::: "memory");
  }
  __builtin_amdgcn_s_barrier();

  const int s0 = (q ^ (l15 & 7)) * 8;
  const int s1 = ((q + 4) ^ (l15 & 7)) * 8;

  bf16x8 aL[2][4], aH[2][4], bL[2][2], bH[2][2];

  for (int t = 0; t < NK; ++t) {
    const int buf = (t & 1) ? 32768 : 0;
    const int nbuf = 32768 - buf;
    const int abase = buf + wm * 8192 + l15 * 64;
    const int bbase = buf + 16384 + (wn >> 1) * 8192 + ((wn & 1) * 64 + l15) * 64;

    // ---- P1
#pragma unroll
    for (int i = 0; i < 4; ++i) {
      aL[0][i] = *(const bf16x8*)&lds[abase + i * 1024 + s0];
      aL[1][i] = *(const bf16x8*)&lds[abase + i * 1024 + s1];
    }
#pragma unroll
    for (int j = 0; j < 2; ++j) {
      bL[0][j] = *(const bf16x8*)&lds[bbase + j * 1024 + s0];
      bL[1][j] = *(const bf16x8*)&lds[bbase + j * 1024 + s1];
    }
    if (t + 1 < NK) STAGE_A(t + 1, 1, nbuf);
    asm volatile("s_waitcnt lgkmcnt(8)" ::: "memory");
    __builtin_amdgcn_s_barrier();
    asm volatile("s_waitcnt lgkmcnt(0)" ::: "memory");
    __builtin_amdgcn_s_setprio(1);
#pragma unroll
    for (int kp = 0; kp < 2; ++kp)
#pragma unroll
      for (int i = 0; i < 4; ++i)
#pragma unroll
        for (int j = 0; j < 2; ++j)
          acc[i][j] = __builtin_amdgcn_mfma_f32_16x16x32_bf16(aL[kp][i], bL[kp][j], acc[i][j], 0, 0, 0);
    __builtin_amdgcn_s_setprio(0);
    asm volatile("" ::: "memory");
    __builtin_amdgcn_s_barrier();

    // ---- P2
#pragma unroll
    for (int j = 0; j < 2; ++j) {
      bH[0][j] = *(const bf16x8*)&lds[bbase + (2 + j) * 1024 + s0];
      bH[1][j] = *(const bf16x8*)&lds[bbase + (2 + j) * 1024 + s1];
    }
    asm volatile("" ::: "memory");
    __builtin_amdgcn_s_barrier();
    asm volatile("s_waitcnt lgkmcnt(0)" ::: "memory");
    __builtin_amdgcn_s_setprio(1);
#pragma unroll
    for (int kp = 0; kp < 2; ++kp)
#pragma unroll
      for (int i = 0; i < 4; ++i)
#pragma unroll
        for (int j = 0; j < 2; ++j)
          acc[i][2 + j] = __builtin_amdgcn_mfma_f32_16x16x32_bf16(aL[kp][i], bH[kp][j], acc[i][2 + j], 0, 0, 0);
    __builtin_amdgcn_s_setprio(0);
    asm volatile("" ::: "memory");
    __builtin_amdgcn_s_barrier();

    // ---- P3
#pragma unroll
    for (int i = 0; i < 4; ++i) {
      aH[0][i] = *(const bf16x8*)&lds[abase + 4096 + i * 1024 + s0];
      aH[1][i] = *(const bf16x8*)&lds[abase + 4096 + i * 1024 + s1];
    }
    if (t + 2 < NK) { STAGE_B(t + 2, 0, buf); STAGE_B(t + 2, 1, buf); }
    asm volatile("" ::: "memory");
    __builtin_amdgcn_s_barrier();
    asm volatile("s_waitcnt lgkmcnt(0)" ::: "memory");
    __builtin_amdgcn_s_setprio(1);
#pragma unroll
    for (int kp = 0; kp < 2; ++kp)
#pragma unroll
      for (int i = 0; i < 4; ++i)
#pragma unroll
        for (int j = 0; j < 2; ++j)
          acc[4 + i][2 + j] = __builtin_amdgcn_mfma_f32_16x16x32_bf16(aH[kp][i], bH[kp][j], acc[4 + i][2 + j], 0, 0, 0);
    __builtin_amdgcn_s_setprio(0);
    asm volatile("" ::: "memory");
    __builtin_amdgcn_s_barrier();

    // ---- P4
    if (t + 2 < NK) {
      STAGE_A(t + 2, 0, buf);
      asm volatile("s_waitcnt vmcnt(6)" ::: "memory");
    } else {
      asm volatile("s_waitcnt vmcnt(0)" ::: "memory");
    }
    __builtin_amdgcn_s_barrier();
    __builtin_amdgcn_s_setprio(1);
#pragma unroll
    for (int kp = 0; kp < 2; ++kp)
#pragma unroll
      for (int i = 0; i < 4; ++i)
#pragma unroll
        for (int j = 0; j < 2; ++j)
          acc[4 + i][j] = __builtin_amdgcn_mfma_f32_16x16x32_bf16(aH[kp][i], bL[kp][j], acc[4 + i][j], 0, 0, 0);
    __builtin_amdgcn_s_setprio(0);
    asm volatile("" ::: "memory");
    __builtin_amdgcn_s_barrier();
  }

  OutT* Cb = C + bz * sC;
  const int colbase = bx * 256 + wn * 64 + l15;
  const int rowbase = by * 256 + wm * 128 + (q << 2);
#pragma unroll
  for (int i = 0; i < 8; ++i)
#pragma unroll
    for (int j = 0; j < 4; ++j) {
      const int col = colbase + j * 16;
#pragma unroll
      for (int r = 0; r < 4; ++r)
        st_out(&Cb[(long)(rowbase + i * 16 + r) * ldc + col], acc[i][j][r]);
    }
}

// Y = xb @ NT^T on the 256^2 core. 256 blocks (64 M-tiles x 4 N-tiles), 1/CU.
// Split from the merged proj so tri/opv/softmax surface in the top-5 profile.
__global__ __launch_bounds__(512, 2)
void gemm256_y(const u16* __restrict__ xb, const u16* __restrict__ NT,
               u16* __restrict__ Yb)
{
  extern __shared__ u16 lds[];
  int L = blockIdx.x;                  // 0..255
  int t = ((L & 7) << 5) | (L >> 3);   // 32 contiguous tiles per XCD
  int bx = t & 3, by = t >> 2;
  gemm_core256<u16>(xb, 1024, 0L, NT, 1024, 0L, Yb, 1024, 0L,
                    1024, bx, by, 0, (int)threadIdx.x, lds);
}

// VT = WvT @ xb^T on the 256^2 core. 256 blocks (4 M-tiles x 64 N-tiles), 1/CU.
__global__ __launch_bounds__(512, 2)
void gemm256_vt(const u16* __restrict__ WvT, const u16* __restrict__ xb,
                u16* __restrict__ VT)
{
  extern __shared__ u16 lds[];
  int L = blockIdx.x;                  // 0..255
  int t = ((L & 7) << 5) | (L >> 3);
  int bx = t & 63, by = t >> 6;
  gemm_core256<u16>(WvT, 1024, 0L, xb, 1024, 0L, VT, 16384, 0L,
                    1024, bx, by, 0, (int)threadIdx.x, lds);
}

// Merged input converts: x (scale 1), Wq (scale 1/32), Wk — one dispatch.
__global__ __launch_bounds__(256)
void cvt_in(const float4* __restrict__ x, const float4* __restrict__ Wq,
            const float4* __restrict__ Wk, u16* __restrict__ xb,
            u16* __restrict__ oq, u16* __restrict__ ok, int n4x, int n4w)
{
  int i = blockIdx.x * 256 + threadIdx.x;
  const float4* src; u16* dst; int k; float scale;
  if (i < n4x)               { src = x;  dst = xb; k = i;            scale = 1.0f; }
  else if (i < n4x + n4w)    { src = Wq; dst = oq; k = i - n4x;      scale = 0.03125f; }
  else if (i < n4x + 2*n4w)  { src = Wk; dst = ok; k = i - n4x - n4w; scale = 1.0f; }
  else return;
  float4 v = src[k];
  ushort4 r;
  r.x = f2bf(v.x * scale); r.y = f2bf(v.y * scale);
  r.z = f2bf(v.z * scale); r.w = f2bf(v.w * scale);
  *(ushort4*)(dst + (long)k * 4) = r;
}

// W (d_in x d_out) fp32 -> W^T (d_out x d_in) bf16, LDS tiled
__global__ __launch_bounds__(256)
void cvt_w(const float* __restrict__ W, u16* __restrict__ O)
{
  const int D = 1024;
  __shared__ float t[64][65];
  int tid = threadIdx.x;
  int c = tid & 63, r = tid >> 6;
  int e0 = blockIdx.x * 64, d0 = blockIdx.y * 64;
  for (int rr = r; rr < 64; rr += 4)
    t[rr][c] = W[(long)(d0 + rr) * D + e0 + c];
  __syncthreads();
  for (int rr = r; rr < 64; rr += 4)
    O[(long)(e0 + rr) * D + d0 + c] = f2bf(t[c][rr]);
}

// causal softmax over bf16 scores, in-place; one block per row, 8 elems/thread.
// Causal trim (R3): threads with i0 >= W = ((row>>7)+1)*128 skip load+store
// (still join barriers/shuffles); [n, W) written as zeros (opv reads it).
__global__ __launch_bounds__(256)
void softmax_bf16(u16* __restrict__ S)
{
  const int T = 2048;
  int row = blockIdx.x & (T - 1);
  u16* Prow = S + (long)blockIdx.x * T;    // (bi*T+row)*T
  int n = row + 1;
  int W = ((row >> 7) + 1) << 7;           // cols opv will read
  int tid = threadIdx.x, lane = tid & 63, wid = tid >> 6;
  int i0 = tid * 8;
  bool act = (i0 < W);

  float v[8];
  float lmax = -3.0e38f;
  if (act) {
    u16x8 pv = *(const u16x8*)(Prow + i0);
#pragma unroll
    for (int j = 0; j < 8; j++) {
      v[j] = (i0 + j < n) ? bf2f(pv[j]) : -3.0e38f;
      lmax = fmaxf(lmax, v[j]);
    }
  }
  __shared__ float red[8];
#pragma unroll
  for (int o = 32; o > 0; o >>= 1) lmax = fmaxf(lmax, __shfl_down(lmax, o, 64));
  if (lane == 0) red[wid] = lmax;
  __syncthreads();
  float m = fmaxf(fmaxf(red[0], red[1]), fmaxf(red[2], red[3]));

  float lsum = 0.f;
  if (act) {
#pragma unroll
    for (int j = 0; j < 8; j++) {
      float e = (i0 + j < n) ? __expf(v[j] - m) : 0.f;
      v[j] = e;
      lsum += e;
    }
  }
#pragma unroll
  for (int o = 32; o > 0; o >>= 1) lsum += __shfl_down(lsum, o, 64);
  if (lane == 0) red[4 + wid] = lsum;
  __syncthreads();
  float inv = 1.0f / (red[4] + red[5] + red[6] + red[7]);

  if (act) {
    u16x8 w;
#pragma unroll
    for (int j = 0; j < 8; j++) w[j] = f2bf(v[j] * inv);
    *(u16x8*)(Prow + i0) = w;
  }
}

extern "C" void kernel_launch(void* const* d_in, const int* in_sizes, int n_in,
                              void* d_out, int out_size, void* d_ws, size_t ws_size,
                              hipStream_t stream)
{
  const int B = 8, T = 2048, D = 1024;
  const float* x  = (const float*)d_in[0];
  const float* Wq = (const float*)d_in[1];
  const float* Wk = (const float*)d_in[2];
  const float* Wv = (const float*)d_in[3];
  float* out = (float*)d_out;
  char* ws = (char*)d_ws;

  // layout (MB): xb 0-32 | WvT 32-34 | NT 34-36 | Yb 36-68 (Wqb@36,Wkb@38 dead
  // after NT gemm) | VT 68-100 | S bf16 @100 (8 MB/batch)
  u16* xb  = (u16*)(ws);
  u16* WvT = (u16*)(ws + (32ul << 20));
  u16* NT  = (u16*)(ws + (34ul << 20));
  u16* Yb  = (u16*)(ws + (36ul << 20));
  u16* Wqb = Yb;                            // transient
  u16* Wkb = (u16*)(ws + (38ul << 20));     // transient
  u16* VT  = (u16*)(ws + (68ul << 20));
  u16* S   = (u16*)(ws + (100ul << 20));

  const size_t OFF_S = 100ul << 20;
  int NB = 8;
  while (NB > 1 && OFF_S + (size_t)NB * T * T * 2 > ws_size) NB >>= 1;

  // one-time: allow 128 KiB dynamic LDS for the 8-phase cores
  static bool attr_done = false;
  if (!attr_done) {
    hipFuncSetAttribute(reinterpret_cast<const void*>(gemm256_y),
                        hipFuncAttributeMaxDynamicSharedMemorySize, 131072);
    hipFuncSetAttribute(reinterpret_cast<const void*>(gemm256_vt),
                        hipFuncAttributeMaxDynamicSharedMemorySize, 131072);
    attr_done = true;
  }

  int n4x = B * T * D / 4, n4w = D * D / 4;
  cvt_in<<<(n4x + 2 * n4w + 255) / 256, 256, 0, stream>>>(
      (const float4*)x, (const float4*)Wq, (const float4*)Wk,
      xb, Wqb, Wkb, n4x, n4w);
  cvt_w<<<dim3(16, 16), 256, 0, stream>>>(Wv, WvT);

  // NT[d',d] = sum_e Wk[d',e] Wq'[d,e]   (scale folded into Wq')
  gemm_rect<u16><<<dim3(64, 1), 256, 0, stream>>>(
      Wkb, D, 0L, Wqb, D, 0L, NT, D, 0L, D, 3, 3);
  // Y = xb @ NT^T ; VT = WvT @ xb^T  (split 256^2 dispatches, 256 blocks each)
  gemm256_y<<<dim3(256, 1), 512, 131072, stream>>>(xb, NT, Yb);
  gemm256_vt<<<dim3(256, 1), 512, 131072, stream>>>(WvT, xb, VT);

  for (int b0 = 0; b0 < B; b0 += NB) {
    gemm_tri<<<dim3(136, NB), 256, 0, stream>>>(
        Yb + (long)b0 * T * D, D, (long)T * D,
        xb + (long)b0 * T * D, D, (long)T * D,
        S, T, (long)T * T, D);
    softmax_bf16<<<NB * T, 256, 0, stream>>>(S);
    gemm_opv<<<dim3(128, NB), 256, 0, stream>>>(
        S, T, (long)T * T,
        VT + (long)b0 * T, B * T, (long)T,
        out + (long)b0 * T * D, D, (long)T * D);
  }
}

// Round 7
// 362.702 us; speedup vs baseline: 1.1087x; 1.0120x over previous
//
#include <hip/hip_runtime.h>

using u16 = unsigned short;
typedef __bf16 bf16x8 __attribute__((ext_vector_type(8)));
typedef unsigned short u16x8 __attribute__((ext_vector_type(8)));
typedef float floatx4 __attribute__((ext_vector_type(4)));

__device__ __forceinline__ u16 f2bf(float f) {
  union { float f; unsigned u; } c; c.f = f;
  unsigned u = c.u;
  u += 0x7fffu + ((u >> 16) & 1u);   // round-to-nearest-even
  return (u16)(u >> 16);
}
__device__ __forceinline__ float bf2f(u16 h) {
  union { unsigned u; float f; } c; c.u = ((unsigned)h) << 16; return c.f;
}

__device__ __forceinline__ void st_out(float* p, float v) { *p = v; }
__device__ __forceinline__ void st_out(u16* p, float v) { *p = f2bf(v); }

__device__ __forceinline__ void load16(const u16* g, u16* l) {
  __builtin_amdgcn_global_load_lds(
      (const __attribute__((address_space(1))) void*)g,
      (__attribute__((address_space(3))) void*)l, 16, 0, 0);
}

#define TILE 128
#define BK 64

// ---------------------------------------------------------------------------
// 128x128 tile GEMM core, NOW 2-phase prefetch (R7): double-buffered LDS,
// STAGE(k+1) issued BEFORE compute(k), single drain at the trailing
// __syncthreads(). DMA latency (L2 ~200cy, HBM ~900cy) flies under the
// ~550cy compute phase instead of being serially exposed (opv was 5300
// cy/K-step, MfmaUtil 18%, all pipes idle -> latency-bound).
// LDS 64 KB -> still 2 blocks/CU. XOR-chunk swizzle -> 0 bank conflicts.
// WAR-safe: STAGE(k+1) targets the buffer compute(k) does NOT read; re-stage
// of a buffer happens only after the barrier that ends its compute.
// ---------------------------------------------------------------------------
template<typename OutT>
__device__ __forceinline__ void gemm_core(
    const u16* __restrict__ A, int lda, long sA,
    const u16* __restrict__ Bt, int ldb, long sB,
    OutT* __restrict__ C, int ldc, long sC,
    int kmax, int bx, int by, int bz, int tid)
{
  __shared__ u16 As[2 * TILE * BK];
  __shared__ u16 Bs[2 * TILE * BK];

  const u16* Ab = A + bz * sA + (long)by * TILE * lda;
  const u16* Bb = Bt + bz * sB + (long)bx * TILE * ldb;

  int lane = tid & 63;
  int wm = ((tid >> 7) & 1) * 64;
  int wn = ((tid >> 6) & 1) * 64;

  floatx4 acc[4][4] = {};
  int arow = wm + (lane & 15);
  int brow = wn + (lane & 15);
  int q = lane >> 4;

  auto STAGE = [&](int k0, int buf) {
#pragma unroll
    for (int h = 0; h < 4; h++) {
      int cc = tid + h * 256;
      int row = cc >> 3, gm = (cc & 7) ^ (row & 7);
      load16(Ab + (long)row * lda + k0 + gm * 8, &As[buf * (TILE * BK) + cc * 8]);
    }
#pragma unroll
    for (int h = 0; h < 4; h++) {
      int cc = tid + h * 256;
      int row = cc >> 3, gm = (cc & 7) ^ (row & 7);
      load16(Bb + (long)row * ldb + k0 + gm * 8, &Bs[buf * (TILE * BK) + cc * 8]);
    }
  };

  STAGE(0, 0);
  __syncthreads();                 // drains vmcnt, then barrier

  const int NK = kmax / BK;
  for (int k = 0; k < NK; ++k) {
    int cur = k & 1;
    if (k + 1 < NK) STAGE((k + 1) * BK, cur ^ 1);   // overlap with compute below

    int cb = cur * (TILE * BK);
#pragma unroll
    for (int kp = 0; kp < 2; kp++) {
      bf16x8 a[4], b[4];
#pragma unroll
      for (int i = 0; i < 4; i++) {
        int r = arow + i * 16;
        a[i] = *(const bf16x8*)&As[cb + (r * 8 + ((kp * 4 + q) ^ (r & 7))) * 8];
      }
#pragma unroll
      for (int j = 0; j < 4; j++) {
        int r = brow + j * 16;
        b[j] = *(const bf16x8*)&Bs[cb + (r * 8 + ((kp * 4 + q) ^ (r & 7))) * 8];
      }
#pragma unroll
      for (int i = 0; i < 4; i++)
#pragma unroll
        for (int j = 0; j < 4; j++)
          acc[i][j] = __builtin_amdgcn_mfma_f32_16x16x32_bf16(a[i], b[j], acc[i][j], 0, 0, 0);
    }
    __syncthreads();               // drain of stage(k+1) happens HERE, post-compute
  }

  // epilogue: C/D layout col=lane&15, row=(lane>>4)*4+reg  [m89-verified]
  OutT* Cb = C + bz * sC;
  int colbase = bx * TILE + wn + (lane & 15);
  int rowbase = by * TILE + wm + ((lane >> 4) << 2);
#pragma unroll
  for (int i = 0; i < 4; i++)
#pragma unroll
    for (int j = 0; j < 4; j++) {
      int col = colbase + j * 16;
#pragma unroll
      for (int r = 0; r < 4; r++)
        st_out(&Cb[(long)(rowbase + i * 16 + r) * ldc + col], acc[i][j][r]);
    }
}

// Small rectangular GEMM (used for NT), XCD-contiguous remap
template<typename OutT>
__global__ __launch_bounds__(256, 2)
void gemm_rect(const u16* __restrict__ A, int lda, long sA,
               const u16* __restrict__ Bt, int ldb, long sB,
               OutT* __restrict__ C, int ldc, long sC, int K,
               int l2gx, int nO8s)
{
  int L = blockIdx.x;
  int t = ((L & 7) << nO8s) | (L >> 3);
  int bx = t & ((1 << l2gx) - 1), by = t >> l2gx;
  gemm_core<OutT>(A, lda, sA, Bt, ldb, sB, C, ldc, sC, K, bx, by, blockIdx.y, threadIdx.x);
}

// Causal S = Y @ x^T -> bf16 scores (scale pre-folded into Wq). 136 tiles/batch.
// 2x2 super-block triangle walk (R3-best): per-XCD working set ~1 MB (L2-fit).
__global__ __launch_bounds__(256, 2)
void gemm_tri(const u16* __restrict__ A, int lda, long sA,
              const u16* __restrict__ Bt, int ldb, long sB,
              u16* __restrict__ C, int ldc, long sC, int K)
{
  int tp = blockIdx.x;                       // 0..135
  int g = (tp & 7) * 17 + (tp >> 3);         // 17 contiguous slots per XCD
  int sr = 0, sc = 0, pre = 0;
  for (;;) {
    int sz = (sr == sc) ? 3 : 4;
    if (pre + sz > g) break;
    pre += sz; ++sc;
    if (sc > sr) { ++sr; sc = 0; }
  }
  int w = g - pre;
  int r, c;
  if (sr == sc) { r = 2 * sr + (w > 0); c = 2 * sc + (w == 2); }
  else          { r = 2 * sr + (w >> 1); c = 2 * sc + (w & 1); }
  gemm_core<u16>(A, lda, sA, Bt, ldb, sB, C, ldc, sC, K, c, r, blockIdx.y, threadIdx.x);
}

// O = P @ V via VT (per-batch layout [B][D][T], ldb=2048 -> 4 KB row stride).
// Causal K-trim; XCD j runs long row (15-j) FIRST, then row j.
__global__ __launch_bounds__(256, 2)
void gemm_opv(const u16* __restrict__ P, int lda, long sA,
              const u16* __restrict__ VT, int ldb, long sB,
              float* __restrict__ C, int ldc, long sC)
{
  int L = blockIdx.x;                        // 0..127
  int j = L & 7, s = L >> 3;
  int by = (s < 8) ? 15 - j : j;
  int bx = s & 7;
  gemm_core<float>(P, lda, sA, VT, ldb, sB, C, ldc, sC,
                   (by + 1) * TILE, bx, by, blockIdx.y, threadIdx.x);
}

// ---------------------------------------------------------------------------
// 256x256-tile, BK=64, 8-wave, 8-phase counted-vmcnt core (frozen since R2).
// ---------------------------------------------------------------------------
template<typename OutT>
__device__ __forceinline__ void gemm_core256(
    const u16* __restrict__ A, int lda, long sA,
    const u16* __restrict__ Bt, int ldb, long sB,
    OutT* __restrict__ C, int ldc, long sC,
    int kmax, int bx, int by, int bz, int tid, u16* lds)
{
  const u16* Ab = A + bz * sA + (long)by * 256 * lda;
  const u16* Bb = Bt + bz * sB + (long)bx * 256 * ldb;

  const int lane = tid & 63, wid = tid >> 6;
  const int wm = wid >> 2;
  const int wn = wid & 3;
  const int l15 = lane & 15, q = lane >> 4;

  const int cc0 = tid, cc1 = tid + 512;
  const int r0 = cc0 >> 3, g0 = (cc0 & 7) ^ (r0 & 7);
  const int r1 = cc1 >> 3, g1 = (cc1 & 7) ^ (r1 & 7);

  const int NK = kmax >> 6;

  floatx4 acc[8][4] = {};

  auto STAGE_A = [&](int k, int half, int buf) {
    const u16* g = Ab + (long)(half * 128) * lda + k * 64;
    load16(g + (long)r0 * lda + g0 * 8, lds + buf + half * 8192 + cc0 * 8);
    load16(g + (long)r1 * lda + g1 * 8, lds + buf + half * 8192 + cc1 * 8);
  };
  auto STAGE_B = [&](int k, int half, int buf) {
    const u16* g = Bb + (long)(half * 128) * ldb + k * 64;
    load16(g + (long)r0 * ldb + g0 * 8, lds + buf + 16384 + half * 8192 + cc0 * 8);
    load16(g + (long)r1 * ldb + g1 * 8, lds + buf + 16384 + half * 8192 + cc1 * 8);
  };

  STAGE_B(0, 0, 0); STAGE_B(0, 1, 0);
  STAGE_A(0, 0, 0); STAGE_A(0, 1, 0);
  if (NK > 1) {
    STAGE_B(1, 0, 32768); STAGE_B(1, 1, 32768);
    STAGE_A(1, 0, 32768);
    asm volatile("s_waitcnt vmcnt(6)" ::: "memory");
  } else {
    asm volatile("s_waitcnt vmcnt(0)" ::: "memory");
  }
  __builtin_amdgcn_s_barrier();

  const int s0 = (q ^ (l15 & 7)) * 8;
  const int s1 = ((q + 4) ^ (l15 & 7)) * 8;

  bf16x8 aL[2][4], aH[2][4], bL[2][2], bH[2][2];

  for (int t = 0; t < NK; ++t) {
    const int buf = (t & 1) ? 32768 : 0;
    const int nbuf = 32768 - buf;
    const int abase = buf + wm * 8192 + l15 * 64;
    const int bbase = buf + 16384 + (wn >> 1) * 8192 + ((wn & 1) * 64 + l15) * 64;

    // ---- P1
#pragma unroll
    for (int i = 0; i < 4; ++i) {
      aL[0][i] = *(const bf16x8*)&lds[abase + i * 1024 + s0];
      aL[1][i] = *(const bf16x8*)&lds[abase + i * 1024 + s1];
    }
#pragma unroll
    for (int j = 0; j < 2; ++j) {
      bL[0][j] = *(const bf16x8*)&lds[bbase + j * 1024 + s0];
      bL[1][j] = *(const bf16x8*)&lds[bbase + j * 1024 + s1];
    }
    if (t + 1 < NK) STAGE_A(t + 1, 1, nbuf);
    asm volatile("s_waitcnt lgkmcnt(8)" ::: "memory");
    __builtin_amdgcn_s_barrier();
    asm volatile("s_waitcnt lgkmcnt(0)" ::: "memory");
    __builtin_amdgcn_s_setprio(1);
#pragma unroll
    for (int kp = 0; kp < 2; ++kp)
#pragma unroll
      for (int i = 0; i < 4; ++i)
#pragma unroll
        for (int j = 0; j < 2; ++j)
          acc[i][j] = __builtin_amdgcn_mfma_f32_16x16x32_bf16(aL[kp][i], bL[kp][j], acc[i][j], 0, 0, 0);
    __builtin_amdgcn_s_setprio(0);
    asm volatile("" ::: "memory");
    __builtin_amdgcn_s_barrier();

    // ---- P2
#pragma unroll
    for (int j = 0; j < 2; ++j) {
      bH[0][j] = *(const bf16x8*)&lds[bbase + (2 + j) * 1024 + s0];
      bH[1][j] = *(const bf16x8*)&lds[bbase + (2 + j) * 1024 + s1];
    }
    asm volatile("" ::: "memory");
    __builtin_amdgcn_s_barrier();
    asm volatile("s_waitcnt lgkmcnt(0)" ::: "memory");
    __builtin_amdgcn_s_setprio(1);
#pragma unroll
    for (int kp = 0; kp < 2; ++kp)
#pragma unroll
      for (int i = 0; i < 4; ++i)
#pragma unroll
        for (int j = 0; j < 2; ++j)
          acc[i][2 + j] = __builtin_amdgcn_mfma_f32_16x16x32_bf16(aL[kp][i], bH[kp][j], acc[i][2 + j], 0, 0, 0);
    __builtin_amdgcn_s_setprio(0);
    asm volatile("" ::: "memory");
    __builtin_amdgcn_s_barrier();

    // ---- P3
#pragma unroll
    for (int i = 0; i < 4; ++i) {
      aH[0][i] = *(const bf16x8*)&lds[abase + 4096 + i * 1024 + s0];
      aH[1][i] = *(const bf16x8*)&lds[abase + 4096 + i * 1024 + s1];
    }
    if (t + 2 < NK) { STAGE_B(t + 2, 0, buf); STAGE_B(t + 2, 1, buf); }
    asm volatile("" ::: "memory");
    __builtin_amdgcn_s_barrier();
    asm volatile("s_waitcnt lgkmcnt(0)" ::: "memory");
    __builtin_amdgcn_s_setprio(1);
#pragma unroll
    for (int kp = 0; kp < 2; ++kp)
#pragma unroll
      for (int i = 0; i < 4; ++i)
#pragma unroll
        for (int j = 0; j < 2; ++j)
          acc[4 + i][2 + j] = __builtin_amdgcn_mfma_f32_16x16x32_bf16(aH[kp][i], bH[kp][j], acc[4 + i][2 + j], 0, 0, 0);
    __builtin_amdgcn_s_setprio(0);
    asm volatile("" ::: "memory");
    __builtin_amdgcn_s_barrier();

    // ---- P4
    if (t + 2 < NK) {
      STAGE_A(t + 2, 0, buf);
      asm volatile("s_waitcnt vmcnt(6)" ::: "memory");
    } else {
      asm volatile("s_waitcnt vmcnt(0)" ::: "memory");
    }
    __builtin_amdgcn_s_barrier();
    __builtin_amdgcn_s_setprio(1);
#pragma unroll
    for (int kp = 0; kp < 2; ++kp)
#pragma unroll
      for (int i = 0; i < 4; ++i)
#pragma unroll
        for (int j = 0; j < 2; ++j)
          acc[4 + i][j] = __builtin_amdgcn_mfma_f32_16x16x32_bf16(aH[kp][i], bL[kp][j], acc[4 + i][j], 0, 0, 0);
    __builtin_amdgcn_s_setprio(0);
    asm volatile("" ::: "memory");
    __builtin_amdgcn_s_barrier();
  }

  OutT* Cb = C + bz * sC;
  const int colbase = bx * 256 + wn * 64 + l15;
  const int rowbase = by * 256 + wm * 128 + (q << 2);
#pragma unroll
  for (int i = 0; i < 8; ++i)
#pragma unroll
    for (int j = 0; j < 4; ++j) {
      const int col = colbase + j * 16;
#pragma unroll
      for (int r = 0; r < 4; ++r)
        st_out(&Cb[(long)(rowbase + i * 16 + r) * ldc + col], acc[i][j][r]);
    }
}

// Merged projections on the 256^2 8-phase core (re-merged: -1 launch gap).
// t<256: Y = xb @ NT^T. t>=256: VT = WvT @ xb^T with per-batch VT layout
// [B][D][T]: column-tile 0..63 maps to batch b = tile>>3 (T/256 = 8 tiles per
// batch, aligned), in-batch tile bx = tile&7; C = VT + b*D*T, ldc = 2048.
__global__ __launch_bounds__(512, 2)
void gemm256_proj(const u16* __restrict__ xb, const u16* __restrict__ NT,
                  const u16* __restrict__ WvT, u16* __restrict__ Yb,
                  u16* __restrict__ VT)
{
  extern __shared__ u16 lds[];
  const int T = 2048, D = 1024;
  int L = blockIdx.x;                  // 0..511
  int t = ((L & 7) << 6) | (L >> 3);   // 64 contiguous tiles per XCD
  if (t < 256) {
    int bx = t & 3, by = t >> 2;
    gemm_core256<u16>(xb, 1024, 0L, NT, 1024, 0L, Yb, 1024, 0L,
                      1024, bx, by, 0, (int)threadIdx.x, lds);
  } else {
    int tt = t - 256;
    int bt = tt & 63, by = tt >> 6;
    int b = bt >> 3, bx = bt & 7;
    gemm_core256<u16>(WvT, 1024, 0L, xb + (long)b * T * D, 1024, 0L,
                      VT + (long)b * D * T, 2048, 0L,
                      1024, bx, by, 0, (int)threadIdx.x, lds);
  }
}

// Merged input converts: x (scale 1), Wq (scale 1/32), Wk — one dispatch.
__global__ __launch_bounds__(256)
void cvt_in(const float4* __restrict__ x, const float4* __restrict__ Wq,
            const float4* __restrict__ Wk, u16* __restrict__ xb,
            u16* __restrict__ oq, u16* __restrict__ ok, int n4x, int n4w)
{
  int i = blockIdx.x * 256 + threadIdx.x;
  const float4* src; u16* dst; int k; float scale;
  if (i < n4x)               { src = x;  dst = xb; k = i;            scale = 1.0f; }
  else if (i < n4x + n4w)    { src = Wq; dst = oq; k = i - n4x;      scale = 0.03125f; }
  else if (i < n4x + 2*n4w)  { src = Wk; dst = ok; k = i - n4x - n4w; scale = 1.0f; }
  else return;
  float4 v = src[k];
  ushort4 r;
  r.x = f2bf(v.x * scale); r.y = f2bf(v.y * scale);
  r.z = f2bf(v.z * scale); r.w = f2bf(v.w * scale);
  *(ushort4*)(dst + (long)k * 4) = r;
}

// W (d_in x d_out) fp32 -> W^T (d_out x d_in) bf16, LDS tiled
__global__ __launch_bounds__(256)
void cvt_w(const float* __restrict__ W, u16* __restrict__ O)
{
  const int D = 1024;
  __shared__ float t[64][65];
  int tid = threadIdx.x;
  int c = tid & 63, r = tid >> 6;
  int e0 = blockIdx.x * 64, d0 = blockIdx.y * 64;
  for (int rr = r; rr < 64; rr += 4)
    t[rr][c] = W[(long)(d0 + rr) * D + e0 + c];
  __syncthreads();
  for (int rr = r; rr < 64; rr += 4)
    O[(long)(e0 + rr) * D + d0 + c] = f2bf(t[c][rr]);
}

// causal softmax over bf16 scores, in-place; one block per row, 8 elems/thread.
// Causal trim (R3): threads with i0 >= W = ((row>>7)+1)*128 skip load+store
// (still join barriers/shuffles); [n, W) written as zeros (opv reads it).
__global__ __launch_bounds__(256)
void softmax_bf16(u16* __restrict__ S)
{
  const int T = 2048;
  int row = blockIdx.x & (T - 1);
  u16* Prow = S + (long)blockIdx.x * T;    // (bi*T+row)*T
  int n = row + 1;
  int W = ((row >> 7) + 1) << 7;           // cols opv will read
  int tid = threadIdx.x, lane = tid & 63, wid = tid >> 6;
  int i0 = tid * 8;
  bool act = (i0 < W);

  float v[8];
  float lmax = -3.0e38f;
  if (act) {
    u16x8 pv = *(const u16x8*)(Prow + i0);
#pragma unroll
    for (int j = 0; j < 8; j++) {
      v[j] = (i0 + j < n) ? bf2f(pv[j]) : -3.0e38f;
      lmax = fmaxf(lmax, v[j]);
    }
  }
  __shared__ float red[8];
#pragma unroll
  for (int o = 32; o > 0; o >>= 1) lmax = fmaxf(lmax, __shfl_down(lmax, o, 64));
  if (lane == 0) red[wid] = lmax;
  __syncthreads();
  float m = fmaxf(fmaxf(red[0], red[1]), fmaxf(red[2], red[3]));

  float lsum = 0.f;
  if (act) {
#pragma unroll
    for (int j = 0; j < 8; j++) {
      float e = (i0 + j < n) ? __expf(v[j] - m) : 0.f;
      v[j] = e;
      lsum += e;
    }
  }
#pragma unroll
  for (int o = 32; o > 0; o >>= 1) lsum += __shfl_down(lsum, o, 64);
  if (lane == 0) red[4 + wid] = lsum;
  __syncthreads();
  float inv = 1.0f / (red[4] + red[5] + red[6] + red[7]);

  if (act) {
    u16x8 w;
#pragma unroll
    for (int j = 0; j < 8; j++) w[j] = f2bf(v[j] * inv);
    *(u16x8*)(Prow + i0) = w;
  }
}

extern "C" void kernel_launch(void* const* d_in, const int* in_sizes, int n_in,
                              void* d_out, int out_size, void* d_ws, size_t ws_size,
                              hipStream_t stream)
{
  const int B = 8, T = 2048, D = 1024;
  const float* x  = (const float*)d_in[0];
  const float* Wq = (const float*)d_in[1];
  const float* Wk = (const float*)d_in[2];
  const float* Wv = (const float*)d_in[3];
  float* out = (float*)d_out;
  char* ws = (char*)d_ws;

  // layout (MB): xb 0-32 | WvT 32-34 | NT 34-36 | Yb 36-68 (Wqb@36,Wkb@38 dead
  // after NT gemm) | VT 68-100 ([B][D][T] per-batch) | S bf16 @100 (8 MB/batch)
  u16* xb  = (u16*)(ws);
  u16* WvT = (u16*)(ws + (32ul << 20));
  u16* NT  = (u16*)(ws + (34ul << 20));
  u16* Yb  = (u16*)(ws + (36ul << 20));
  u16* Wqb = Yb;                            // transient
  u16* Wkb = (u16*)(ws + (38ul << 20));     // transient
  u16* VT  = (u16*)(ws + (68ul << 20));
  u16* S   = (u16*)(ws + (100ul << 20));

  const size_t OFF_S = 100ul << 20;
  int NB = 8;
  while (NB > 1 && OFF_S + (size_t)NB * T * T * 2 > ws_size) NB >>= 1;

  // one-time: allow 128 KiB dynamic LDS for the 8-phase core
  static bool attr_done = false;
  if (!attr_done) {
    hipFuncSetAttribute(reinterpret_cast<const void*>(gemm256_proj),
                        hipFuncAttributeMaxDynamicSharedMemorySize, 131072);
    attr_done = true;
  }

  int n4x = B * T * D / 4, n4w = D * D / 4;
  cvt_in<<<(n4x + 2 * n4w + 255) / 256, 256, 0, stream>>>(
      (const float4*)x, (const float4*)Wq, (const float4*)Wk,
      xb, Wqb, Wkb, n4x, n4w);
  cvt_w<<<dim3(16, 16), 256, 0, stream>>>(Wv, WvT);

  // NT[d',d] = sum_e Wk[d',e] Wq'[d,e]   (scale folded into Wq')
  gemm_rect<u16><<<dim3(64, 1), 256, 0, stream>>>(
      Wkb, D, 0L, Wqb, D, 0L, NT, D, 0L, D, 3, 3);
  // Y = xb @ NT^T  and  VT = WvT @ xb^T (per-batch layout) in one dispatch
  gemm256_proj<<<dim3(512, 1), 512, 131072, stream>>>(xb, NT, WvT, Yb, VT);

  for (int b0 = 0; b0 < B; b0 += NB) {
    gemm_tri<<<dim3(136, NB), 256, 0, stream>>>(
        Yb + (long)b0 * T * D, D, (long)T * D,
        xb + (long)b0 * T * D, D, (long)T * D,
        S, T, (long)T * T, D);
    softmax_bf16<<<NB * T, 256, 0, stream>>>(S);
    gemm_opv<<<dim3(128, NB), 256, 0, stream>>>(
        S, T, (long)T * T,
        VT + (long)b0 * D * T, 2048, (long)D * T,
        out + (long)b0 * T * D, D, (long)T * D);
  }
}

// Round 8
// 362.384 us; speedup vs baseline: 1.1096x; 1.0009x over previous
//
#include <hip/hip_runtime.h>

using u16 = unsigned short;
typedef __bf16 bf16x8 __attribute__((ext_vector_type(8)));
typedef unsigned short u16x8 __attribute__((ext_vector_type(8)));
typedef float floatx4 __attribute__((ext_vector_type(4)));

__device__ __forceinline__ u16 f2bf(float f) {
  union { float f; unsigned u; } c; c.f = f;
  unsigned u = c.u;
  u += 0x7fffu + ((u >> 16) & 1u);   // round-to-nearest-even
  return (u16)(u >> 16);
}
__device__ __forceinline__ float bf2f(u16 h) {
  union { unsigned u; float f; } c; c.u = ((unsigned)h) << 16; return c.f;
}

__device__ __forceinline__ void st_out(float* p, float v) { *p = v; }
__device__ __forceinline__ void st_out(u16* p, float v) { *p = f2bf(v); }

__device__ __forceinline__ void load16(const u16* g, u16* l) {
  __builtin_amdgcn_global_load_lds(
      (const __attribute__((address_space(1))) void*)g,
      (__attribute__((address_space(3))) void*)l, 16, 0, 0);
}

#define TILE 128
#define BK 64

// ---------------------------------------------------------------------------
// 128x128 tile GEMM core, 2-phase prefetch (R7): double-buffered LDS,
// STAGE(k+1) issued BEFORE compute(k), single drain at the trailing
// __syncthreads(). XOR-chunk swizzle -> 0 bank conflicts. 64 KB LDS, 2/CU.
// ---------------------------------------------------------------------------
template<typename OutT>
__device__ __forceinline__ void gemm_core(
    const u16* __restrict__ A, int lda, long sA,
    const u16* __restrict__ Bt, int ldb, long sB,
    OutT* __restrict__ C, int ldc, long sC,
    int kmax, int bx, int by, int bz, int tid)
{
  __shared__ u16 As[2 * TILE * BK];
  __shared__ u16 Bs[2 * TILE * BK];

  const u16* Ab = A + bz * sA + (long)by * TILE * lda;
  const u16* Bb = Bt + bz * sB + (long)bx * TILE * ldb;

  int lane = tid & 63;
  int wm = ((tid >> 7) & 1) * 64;
  int wn = ((tid >> 6) & 1) * 64;

  floatx4 acc[4][4] = {};
  int arow = wm + (lane & 15);
  int brow = wn + (lane & 15);
  int q = lane >> 4;

  auto STAGE = [&](int k0, int buf) {
#pragma unroll
    for (int h = 0; h < 4; h++) {
      int cc = tid + h * 256;
      int row = cc >> 3, gm = (cc & 7) ^ (row & 7);
      load16(Ab + (long)row * lda + k0 + gm * 8, &As[buf * (TILE * BK) + cc * 8]);
    }
#pragma unroll
    for (int h = 0; h < 4; h++) {
      int cc = tid + h * 256;
      int row = cc >> 3, gm = (cc & 7) ^ (row & 7);
      load16(Bb + (long)row * ldb + k0 + gm * 8, &Bs[buf * (TILE * BK) + cc * 8]);
    }
  };

  STAGE(0, 0);
  __syncthreads();                 // drains vmcnt, then barrier

  const int NK = kmax / BK;
  for (int k = 0; k < NK; ++k) {
    int cur = k & 1;
    if (k + 1 < NK) STAGE((k + 1) * BK, cur ^ 1);   // overlap with compute below

    int cb = cur * (TILE * BK);
#pragma unroll
    for (int kp = 0; kp < 2; kp++) {
      bf16x8 a[4], b[4];
#pragma unroll
      for (int i = 0; i < 4; i++) {
        int r = arow + i * 16;
        a[i] = *(const bf16x8*)&As[cb + (r * 8 + ((kp * 4 + q) ^ (r & 7))) * 8];
      }
#pragma unroll
      for (int j = 0; j < 4; j++) {
        int r = brow + j * 16;
        b[j] = *(const bf16x8*)&Bs[cb + (r * 8 + ((kp * 4 + q) ^ (r & 7))) * 8];
      }
#pragma unroll
      for (int i = 0; i < 4; i++)
#pragma unroll
        for (int j = 0; j < 4; j++)
          acc[i][j] = __builtin_amdgcn_mfma_f32_16x16x32_bf16(a[i], b[j], acc[i][j], 0, 0, 0);
    }
    __syncthreads();               // drain of stage(k+1) happens HERE, post-compute
  }

  // epilogue: C/D layout col=lane&15, row=(lane>>4)*4+reg  [m89-verified]
  OutT* Cb = C + bz * sC;
  int colbase = bx * TILE + wn + (lane & 15);
  int rowbase = by * TILE + wm + ((lane >> 4) << 2);
#pragma unroll
  for (int i = 0; i < 4; i++)
#pragma unroll
    for (int j = 0; j < 4; j++) {
      int col = colbase + j * 16;
#pragma unroll
      for (int r = 0; r < 4; r++)
        st_out(&Cb[(long)(rowbase + i * 16 + r) * ldc + col], acc[i][j][r]);
    }
}

// Small rectangular GEMM (used for NT), XCD-contiguous remap
template<typename OutT>
__global__ __launch_bounds__(256, 2)
void gemm_rect(const u16* __restrict__ A, int lda, long sA,
               const u16* __restrict__ Bt, int ldb, long sB,
               OutT* __restrict__ C, int ldc, long sC, int K,
               int l2gx, int nO8s)
{
  int L = blockIdx.x;
  int t = ((L & 7) << nO8s) | (L >> 3);
  int bx = t & ((1 << l2gx) - 1), by = t >> l2gx;
  gemm_core<OutT>(A, lda, sA, Bt, ldb, sB, C, ldc, sC, K, bx, by, blockIdx.y, threadIdx.x);
}

// Causal S = Y @ x^T -> bf16 scores (scale pre-folded into Wq). 136 tiles/batch.
// 2x2 super-block triangle walk (R3-best): per-XCD working set ~1 MB (L2-fit).
__global__ __launch_bounds__(256, 2)
void gemm_tri(const u16* __restrict__ A, int lda, long sA,
              const u16* __restrict__ Bt, int ldb, long sB,
              u16* __restrict__ C, int ldc, long sC, int K)
{
  int tp = blockIdx.x;                       // 0..135
  int g = (tp & 7) * 17 + (tp >> 3);         // 17 contiguous slots per XCD
  int sr = 0, sc = 0, pre = 0;
  for (;;) {
    int sz = (sr == sc) ? 3 : 4;
    if (pre + sz > g) break;
    pre += sz; ++sc;
    if (sc > sr) { ++sr; sc = 0; }
  }
  int w = g - pre;
  int r, c;
  if (sr == sc) { r = 2 * sr + (w > 0); c = 2 * sc + (w == 2); }
  else          { r = 2 * sr + (w >> 1); c = 2 * sc + (w & 1); }
  gemm_core<u16>(A, lda, sA, Bt, ldb, sB, C, ldc, sC, K, c, r, blockIdx.y, threadIdx.x);
}

// O = P @ V via VT (per-batch layout [B][D][T], ldb=2048 -> 4 KB row stride).
// Causal K-trim; XCD j runs long row (15-j) FIRST, then row j.
__global__ __launch_bounds__(256, 2)
void gemm_opv(const u16* __restrict__ P, int lda, long sA,
              const u16* __restrict__ VT, int ldb, long sB,
              float* __restrict__ C, int ldc, long sC)
{
  int L = blockIdx.x;                        // 0..127
  int j = L & 7, s = L >> 3;
  int by = (s < 8) ? 15 - j : j;
  int bx = s & 7;
  gemm_core<float>(P, lda, sA, VT, ldb, sB, C, ldc, sC,
                   (by + 1) * TILE, bx, by, blockIdx.y, threadIdx.x);
}

// ---------------------------------------------------------------------------
// 256x256-tile, BK=64, 8-wave, 8-phase counted-vmcnt core (frozen since R2).
// ---------------------------------------------------------------------------
template<typename OutT>
__device__ __forceinline__ void gemm_core256(
    const u16* __restrict__ A, int lda, long sA,
    const u16* __restrict__ Bt, int ldb, long sB,
    OutT* __restrict__ C, int ldc, long sC,
    int kmax, int bx, int by, int bz, int tid, u16* lds)
{
  const u16* Ab = A + bz * sA + (long)by * 256 * lda;
  const u16* Bb = Bt + bz * sB + (long)bx * 256 * ldb;

  const int lane = tid & 63, wid = tid >> 6;
  const int wm = wid >> 2;
  const int wn = wid & 3;
  const int l15 = lane & 15, q = lane >> 4;

  const int cc0 = tid, cc1 = tid + 512;
  const int r0 = cc0 >> 3, g0 = (cc0 & 7) ^ (r0 & 7);
  const int r1 = cc1 >> 3, g1 = (cc1 & 7) ^ (r1 & 7);

  const int NK = kmax >> 6;

  floatx4 acc[8][4] = {};

  auto STAGE_A = [&](int k, int half, int buf) {
    const u16* g = Ab + (long)(half * 128) * lda + k * 64;
    load16(g + (long)r0 * lda + g0 * 8, lds + buf + half * 8192 + cc0 * 8);
    load16(g + (long)r1 * lda + g1 * 8, lds + buf + half * 8192 + cc1 * 8);
  };
  auto STAGE_B = [&](int k, int half, int buf) {
    const u16* g = Bb + (long)(half * 128) * ldb + k * 64;
    load16(g + (long)r0 * ldb + g0 * 8, lds + buf + 16384 + half * 8192 + cc0 * 8);
    load16(g + (long)r1 * ldb + g1 * 8, lds + buf + 16384 + half * 8192 + cc1 * 8);
  };

  STAGE_B(0, 0, 0); STAGE_B(0, 1, 0);
  STAGE_A(0, 0, 0); STAGE_A(0, 1, 0);
  if (NK > 1) {
    STAGE_B(1, 0, 32768); STAGE_B(1, 1, 32768);
    STAGE_A(1, 0, 32768);
    asm volatile("s_waitcnt vmcnt(6)" ::: "memory");
  } else {
    asm volatile("s_waitcnt vmcnt(0)" ::: "memory");
  }
  __builtin_amdgcn_s_barrier();

  const int s0 = (q ^ (l15 & 7)) * 8;
  const int s1 = ((q + 4) ^ (l15 & 7)) * 8;

  bf16x8 aL[2][4], aH[2][4], bL[2][2], bH[2][2];

  for (int t = 0; t < NK; ++t) {
    const int buf = (t & 1) ? 32768 : 0;
    const int nbuf = 32768 - buf;
    const int abase = buf + wm * 8192 + l15 * 64;
    const int bbase = buf + 16384 + (wn >> 1) * 8192 + ((wn & 1) * 64 + l15) * 64;

    // ---- P1
#pragma unroll
    for (int i = 0; i < 4; ++i) {
      aL[0][i] = *(const bf16x8*)&lds[abase + i * 1024 + s0];
      aL[1][i] = *(const bf16x8*)&lds[abase + i * 1024 + s1];
    }
#pragma unroll
    for (int j = 0; j < 2; ++j) {
      bL[0][j] = *(const bf16x8*)&lds[bbase + j * 1024 + s0];
      bL[1][j] = *(const bf16x8*)&lds[bbase + j * 1024 + s1];
    }
    if (t + 1 < NK) STAGE_A(t + 1, 1, nbuf);
    asm volatile("s_waitcnt lgkmcnt(8)" ::: "memory");
    __builtin_amdgcn_s_barrier();
    asm volatile("s_waitcnt lgkmcnt(0)" ::: "memory");
    __builtin_amdgcn_s_setprio(1);
#pragma unroll
    for (int kp = 0; kp < 2; ++kp)
#pragma unroll
      for (int i = 0; i < 4; ++i)
#pragma unroll
        for (int j = 0; j < 2; ++j)
          acc[i][j] = __builtin_amdgcn_mfma_f32_16x16x32_bf16(aL[kp][i], bL[kp][j], acc[i][j], 0, 0, 0);
    __builtin_amdgcn_s_setprio(0);
    asm volatile("" ::: "memory");
    __builtin_amdgcn_s_barrier();

    // ---- P2
#pragma unroll
    for (int j = 0; j < 2; ++j) {
      bH[0][j] = *(const bf16x8*)&lds[bbase + (2 + j) * 1024 + s0];
      bH[1][j] = *(const bf16x8*)&lds[bbase + (2 + j) * 1024 + s1];
    }
    asm volatile("" ::: "memory");
    __builtin_amdgcn_s_barrier();
    asm volatile("s_waitcnt lgkmcnt(0)" ::: "memory");
    __builtin_amdgcn_s_setprio(1);
#pragma unroll
    for (int kp = 0; kp < 2; ++kp)
#pragma unroll
      for (int i = 0; i < 4; ++i)
#pragma unroll
        for (int j = 0; j < 2; ++j)
          acc[i][2 + j] = __builtin_amdgcn_mfma_f32_16x16x32_bf16(aL[kp][i], bH[kp][j], acc[i][2 + j], 0, 0, 0);
    __builtin_amdgcn_s_setprio(0);
    asm volatile("" ::: "memory");
    __builtin_amdgcn_s_barrier();

    // ---- P3
#pragma unroll
    for (int i = 0; i < 4; ++i) {
      aH[0][i] = *(const bf16x8*)&lds[abase + 4096 + i * 1024 + s0];
      aH[1][i] = *(const bf16x8*)&lds[abase + 4096 + i * 1024 + s1];
    }
    if (t + 2 < NK) { STAGE_B(t + 2, 0, buf); STAGE_B(t + 2, 1, buf); }
    asm volatile("" ::: "memory");
    __builtin_amdgcn_s_barrier();
    asm volatile("s_waitcnt lgkmcnt(0)" ::: "memory");
    __builtin_amdgcn_s_setprio(1);
#pragma unroll
    for (int kp = 0; kp < 2; ++kp)
#pragma unroll
      for (int i = 0; i < 4; ++i)
#pragma unroll
        for (int j = 0; j < 2; ++j)
          acc[4 + i][2 + j] = __builtin_amdgcn_mfma_f32_16x16x32_bf16(aH[kp][i], bH[kp][j], acc[4 + i][2 + j], 0, 0, 0);
    __builtin_amdgcn_s_setprio(0);
    asm volatile("" ::: "memory");
    __builtin_amdgcn_s_barrier();

    // ---- P4
    if (t + 2 < NK) {
      STAGE_A(t + 2, 0, buf);
      asm volatile("s_waitcnt vmcnt(6)" ::: "memory");
    } else {
      asm volatile("s_waitcnt vmcnt(0)" ::: "memory");
    }
    __builtin_amdgcn_s_barrier();
    __builtin_amdgcn_s_setprio(1);
#pragma unroll
    for (int kp = 0; kp < 2; ++kp)
#pragma unroll
      for (int i = 0; i < 4; ++i)
#pragma unroll
        for (int j = 0; j < 2; ++j)
          acc[4 + i][j] = __builtin_amdgcn_mfma_f32_16x16x32_bf16(aH[kp][i], bL[kp][j], acc[4 + i][j], 0, 0, 0);
    __builtin_amdgcn_s_setprio(0);
    asm volatile("" ::: "memory");
    __builtin_amdgcn_s_barrier();
  }

  OutT* Cb = C + bz * sC;
  const int colbase = bx * 256 + wn * 64 + l15;
  const int rowbase = by * 256 + wm * 128 + (q << 2);
#pragma unroll
  for (int i = 0; i < 8; ++i)
#pragma unroll
    for (int j = 0; j < 4; ++j) {
      const int col = colbase + j * 16;
#pragma unroll
      for (int r = 0; r < 4; ++r)
        st_out(&Cb[(long)(rowbase + i * 16 + r) * ldc + col], acc[i][j][r]);
    }
}

// Merged projections on the 256^2 8-phase core.
// t<256: Y = xb @ NT^T. t>=256: VT = WvT @ xb^T with per-batch VT layout
// [B][D][T] (b = tile>>3, bx = tile&7, ldc = 2048).
__global__ __launch_bounds__(512, 2)
void gemm256_proj(const u16* __restrict__ xb, const u16* __restrict__ NT,
                  const u16* __restrict__ WvT, u16* __restrict__ Yb,
                  u16* __restrict__ VT)
{
  extern __shared__ u16 lds[];
  const int T = 2048, D = 1024;
  int L = blockIdx.x;                  // 0..511
  int t = ((L & 7) << 6) | (L >> 3);   // 64 contiguous tiles per XCD
  if (t < 256) {
    int bx = t & 3, by = t >> 2;
    gemm_core256<u16>(xb, 1024, 0L, NT, 1024, 0L, Yb, 1024, 0L,
                      1024, bx, by, 0, (int)threadIdx.x, lds);
  } else {
    int tt = t - 256;
    int bt = tt & 63, by = tt >> 6;
    int b = bt >> 3, bx = bt & 7;
    gemm_core256<u16>(WvT, 1024, 0L, xb + (long)b * T * D, 1024, 0L,
                      VT + (long)b * D * T, 2048, 0L,
                      1024, bx, by, 0, (int)threadIdx.x, lds);
  }
}

// ---------------------------------------------------------------------------
// Merged input converts (R8): linear x/Wq/Wk casts AND the Wv transpose in one
// dispatch. Branch is block-uniform (barriers only in the transpose path).
// ---------------------------------------------------------------------------
__global__ __launch_bounds__(256)
void cvt_all(const float4* __restrict__ x, const float4* __restrict__ Wq,
             const float4* __restrict__ Wk, const float* __restrict__ Wv,
             u16* __restrict__ xb, u16* __restrict__ oq, u16* __restrict__ ok,
             u16* __restrict__ wvt, int n4x, int n4w, int nb_lin)
{
  const int D = 1024;
  if ((int)blockIdx.x < nb_lin) {
    int i = blockIdx.x * 256 + threadIdx.x;
    const float4* src; u16* dst; int k; float scale;
    if (i < n4x)               { src = x;  dst = xb; k = i;             scale = 1.0f; }
    else if (i < n4x + n4w)    { src = Wq; dst = oq; k = i - n4x;       scale = 0.03125f; }
    else if (i < n4x + 2*n4w)  { src = Wk; dst = ok; k = i - n4x - n4w; scale = 1.0f; }
    else return;
    float4 v = src[k];
    ushort4 r;
    r.x = f2bf(v.x * scale); r.y = f2bf(v.y * scale);
    r.z = f2bf(v.z * scale); r.w = f2bf(v.w * scale);
    *(ushort4*)(dst + (long)k * 4) = r;
  } else {
    // Wv (d_in x d_out) fp32 -> WvT (d_out x d_in) bf16, LDS tiled
    __shared__ float t[64][65];
    int bb = blockIdx.x - nb_lin;            // 0..255
    int tid = threadIdx.x;
    int c = tid & 63, r = tid >> 6;
    int e0 = (bb & 15) * 64, d0 = (bb >> 4) * 64;
    for (int rr = r; rr < 64; rr += 4)
      t[rr][c] = Wv[(long)(d0 + rr) * D + e0 + c];
    __syncthreads();
    for (int rr = r; rr < 64; rr += 4)
      wvt[(long)(e0 + rr) * D + d0 + c] = f2bf(t[c][rr]);
  }
}

// ---------------------------------------------------------------------------
// Wave-per-row causal softmax (R8): one 64-lane wave owns a whole row in
// registers (<=4 predicated u16x8 chunks = <=32 f32/lane), reductions via
// __shfl_xor — NO LDS, NO barriers (the old one-row-per-block version paid 2
// block barriers + LDS round trips + 16384-block launch; this is 4096 blocks).
// Same trimmed window W = ((row>>7)+1)*128; [n, W) written as zeros (opv reads
// it). Max is bit-identical to the old reduction; sum differs only in fp32
// association (output bf16-rounded — no observable change).
// ---------------------------------------------------------------------------
__global__ __launch_bounds__(256)
void softmax_wave(u16* __restrict__ S)
{
  const int T = 2048;
  int gr = blockIdx.x * 4 + (threadIdx.x >> 6);   // global row id (bi*T + row)
  int lane = threadIdx.x & 63;
  int row = gr & (T - 1);
  u16* Prow = S + (long)gr * T;
  int n = row + 1;
  int W = ((row >> 7) + 1) << 7;

  float v[4][8];
  float lmax = -3.0e38f;
#pragma unroll
  for (int c = 0; c < 4; c++) {
    int i0 = c * 512 + lane * 8;
    if (i0 < W) {
      u16x8 pv = *(const u16x8*)(Prow + i0);
#pragma unroll
      for (int j = 0; j < 8; j++) {
        float f = (i0 + j < n) ? bf2f(pv[j]) : -3.0e38f;
        v[c][j] = f;
        lmax = fmaxf(lmax, f);
      }
    }
  }
#pragma unroll
  for (int o = 32; o > 0; o >>= 1) lmax = fmaxf(lmax, __shfl_xor(lmax, o, 64));

  float lsum = 0.f;
#pragma unroll
  for (int c = 0; c < 4; c++) {
    int i0 = c * 512 + lane * 8;
    if (i0 < W) {
#pragma unroll
      for (int j = 0; j < 8; j++) {
        float e = (i0 + j < n) ? __expf(v[c][j] - lmax) : 0.f;
        v[c][j] = e;
        lsum += e;
      }
    }
  }
#pragma unroll
  for (int o = 32; o > 0; o >>= 1) lsum += __shfl_xor(lsum, o, 64);
  float inv = 1.0f / lsum;

#pragma unroll
  for (int c = 0; c < 4; c++) {
    int i0 = c * 512 + lane * 8;
    if (i0 < W) {
      u16x8 w;
#pragma unroll
      for (int j = 0; j < 8; j++) w[j] = f2bf(v[c][j] * inv);
      *(u16x8*)(Prow + i0) = w;
    }
  }
}

extern "C" void kernel_launch(void* const* d_in, const int* in_sizes, int n_in,
                              void* d_out, int out_size, void* d_ws, size_t ws_size,
                              hipStream_t stream)
{
  const int B = 8, T = 2048, D = 1024;
  const float* x  = (const float*)d_in[0];
  const float* Wq = (const float*)d_in[1];
  const float* Wk = (const float*)d_in[2];
  const float* Wv = (const float*)d_in[3];
  float* out = (float*)d_out;
  char* ws = (char*)d_ws;

  // layout (MB): xb 0-32 | WvT 32-34 | NT 34-36 | Yb 36-68 (Wqb@36,Wkb@38 dead
  // after NT gemm) | VT 68-100 ([B][D][T] per-batch) | S bf16 @100 (8 MB/batch)
  u16* xb  = (u16*)(ws);
  u16* WvT = (u16*)(ws + (32ul << 20));
  u16* NT  = (u16*)(ws + (34ul << 20));
  u16* Yb  = (u16*)(ws + (36ul << 20));
  u16* Wqb = Yb;                            // transient
  u16* Wkb = (u16*)(ws + (38ul << 20));     // transient
  u16* VT  = (u16*)(ws + (68ul << 20));
  u16* S   = (u16*)(ws + (100ul << 20));

  const size_t OFF_S = 100ul << 20;
  int NB = 8;
  while (NB > 1 && OFF_S + (size_t)NB * T * T * 2 > ws_size) NB >>= 1;

  // one-time: allow 128 KiB dynamic LDS for the 8-phase core
  static bool attr_done = false;
  if (!attr_done) {
    hipFuncSetAttribute(reinterpret_cast<const void*>(gemm256_proj),
                        hipFuncAttributeMaxDynamicSharedMemorySize, 131072);
    attr_done = true;
  }

  int n4x = B * T * D / 4, n4w = D * D / 4;
  int nb_lin = (n4x + 2 * n4w + 255) / 256;   // 18432
  cvt_all<<<nb_lin + 256, 256, 0, stream>>>(
      (const float4*)x, (const float4*)Wq, (const float4*)Wk, Wv,
      xb, Wqb, Wkb, WvT, n4x, n4w, nb_lin);

  // NT[d',d] = sum_e Wk[d',e] Wq'[d,e]   (scale folded into Wq')
  gemm_rect<u16><<<dim3(64, 1), 256, 0, stream>>>(
      Wkb, D, 0L, Wqb, D, 0L, NT, D, 0L, D, 3, 3);
  // Y = xb @ NT^T  and  VT = WvT @ xb^T (per-batch layout) in one dispatch
  gemm256_proj<<<dim3(512, 1), 512, 131072, stream>>>(xb, NT, WvT, Yb, VT);

  for (int b0 = 0; b0 < B; b0 += NB) {
    gemm_tri<<<dim3(136, NB), 256, 0, stream>>>(
        Yb + (long)b0 * T * D, D, (long)T * D,
        xb + (long)b0 * T * D, D, (long)T * D,
        S, T, (long)T * T, D);
    softmax_wave<<<NB * T / 4, 256, 0, stream>>>(S);
    gemm_opv<<<dim3(128, NB), 256, 0, stream>>>(
        S, T, (long)T * T,
        VT + (long)b0 * D * T, 2048, (long)D * T,
        out + (long)b0 * T * D, D, (long)T * D);
  }
}

// Round 9
// 345.554 us; speedup vs baseline: 1.1637x; 1.0487x over previous
//
#include <hip/hip_runtime.h>

using u16 = unsigned short;
typedef __bf16 bf16x8 __attribute__((ext_vector_type(8)));
typedef unsigned short u16x8 __attribute__((ext_vector_type(8)));
typedef float floatx4 __attribute__((ext_vector_type(4)));

__device__ __forceinline__ u16 f2bf(float f) {
  union { float f; unsigned u; } c; c.f = f;
  unsigned u = c.u;
  u += 0x7fffu + ((u >> 16) & 1u);   // round-to-nearest-even
  return (u16)(u >> 16);
}
__device__ __forceinline__ float bf2f(u16 h) {
  union { unsigned u; float f; } c; c.u = ((unsigned)h) << 16; return c.f;
}

__device__ __forceinline__ void st_out(float* p, float v) { *p = v; }
__device__ __forceinline__ void st_out(u16* p, float v) { *p = f2bf(v); }

__device__ __forceinline__ void load16(const u16* g, u16* l) {
  __builtin_amdgcn_global_load_lds(
      (const __attribute__((address_space(1))) void*)g,
      (__attribute__((address_space(3))) void*)l, 16, 0, 0);
}

// Inline-asm ds_read_b128: invisible to the compiler's LDS-DMA alias tracking,
// so it can NOT auto-insert s_waitcnt vmcnt(0) before it (R9 theory: that
// auto-drain was collapsing every prefetch schedule back to full-serial).
// Caller MUST provide explicit s_waitcnt lgkmcnt + sched_barrier(0) (rule #18).
__device__ __forceinline__ bf16x8 ldsread(const u16* p) {
  bf16x8 d;
  const __attribute__((address_space(3))) u16* lp =
      (const __attribute__((address_space(3))) u16*)p;
  asm volatile("ds_read_b128 %0, %1" : "=v"(d) : "v"(lp));
  return d;
}

#define TILE 128
#define BK 64

// ---------------------------------------------------------------------------
// 128x128 tile GEMM core (R9): 2-phase prefetch with COUNTED vmcnt.
// Loop: STAGE(k+1)->buf^1 ; vmcnt(8) [waits only tile k's 8 loads — tile k+1's
// stay in flight across the barrier] ; s_barrier ; asm ds_reads + lgkmcnt(0) +
// sched_barrier(0) + MFMA ; s_barrier [WAR: reads drained above].
// Invariant: 8 outstanding loads at loop top (16 after issue; vmcnt retires in
// issue order). Final iter: vmcnt(0). XOR-chunk swizzle -> 0 bank conflicts.
// ---------------------------------------------------------------------------
template<typename OutT>
__device__ __forceinline__ void gemm_core(
    const u16* __restrict__ A, int lda, long sA,
    const u16* __restrict__ Bt, int ldb, long sB,
    OutT* __restrict__ C, int ldc, long sC,
    int kmax, int bx, int by, int bz, int tid)
{
  __shared__ u16 As[2 * TILE * BK];
  __shared__ u16 Bs[2 * TILE * BK];

  const u16* Ab = A + bz * sA + (long)by * TILE * lda;
  const u16* Bb = Bt + bz * sB + (long)bx * TILE * ldb;

  int lane = tid & 63;
  int wm = ((tid >> 7) & 1) * 64;
  int wn = ((tid >> 6) & 1) * 64;

  floatx4 acc[4][4] = {};
  int arow = wm + (lane & 15);
  int brow = wn + (lane & 15);
  int q = lane >> 4;

  auto STAGE = [&](int k0, int buf) {
#pragma unroll
    for (int h = 0; h < 4; h++) {
      int cc = tid + h * 256;
      int row = cc >> 3, gm = (cc & 7) ^ (row & 7);
      load16(Ab + (long)row * lda + k0 + gm * 8, &As[buf * (TILE * BK) + cc * 8]);
    }
#pragma unroll
    for (int h = 0; h < 4; h++) {
      int cc = tid + h * 256;
      int row = cc >> 3, gm = (cc & 7) ^ (row & 7);
      load16(Bb + (long)row * ldb + k0 + gm * 8, &Bs[buf * (TILE * BK) + cc * 8]);
    }
  };

  STAGE(0, 0);                     // 8 loads in flight

  const int NK = kmax / BK;
  for (int k = 0; k < NK; ++k) {
    int cur = k & 1;
    if (k + 1 < NK) {
      STAGE((k + 1) * BK, cur ^ 1);                     // +8 -> 16 in flight
      asm volatile("s_waitcnt vmcnt(8)" ::: "memory");  // tile k landed; k+1 in flight
    } else {
      asm volatile("s_waitcnt vmcnt(0)" ::: "memory");
    }
    __builtin_amdgcn_s_barrier();

    int cb = cur * (TILE * BK);
#pragma unroll
    for (int kp = 0; kp < 2; kp++) {
      bf16x8 a[4], b[4];
#pragma unroll
      for (int i = 0; i < 4; i++) {
        int r = arow + i * 16;
        a[i] = ldsread(&As[cb + (r * 8 + ((kp * 4 + q) ^ (r & 7))) * 8]);
      }
#pragma unroll
      for (int j = 0; j < 4; j++) {
        int r = brow + j * 16;
        b[j] = ldsread(&Bs[cb + (r * 8 + ((kp * 4 + q) ^ (r & 7))) * 8]);
      }
      asm volatile("s_waitcnt lgkmcnt(0)" ::: "memory");
      __builtin_amdgcn_sched_barrier(0);                // rule #18: pin MFMAs below wait
#pragma unroll
      for (int i = 0; i < 4; i++)
#pragma unroll
        for (int j = 0; j < 4; j++)
          acc[i][j] = __builtin_amdgcn_mfma_f32_16x16x32_bf16(a[i], b[j], acc[i][j], 0, 0, 0);
    }
    __builtin_amdgcn_s_barrier();   // WAR: all waves' reads of buf done (lgkm drained)
  }

  // epilogue: C/D layout col=lane&15, row=(lane>>4)*4+reg  [m89-verified]
  OutT* Cb = C + bz * sC;
  int colbase = bx * TILE + wn + (lane & 15);
  int rowbase = by * TILE + wm + ((lane >> 4) << 2);
#pragma unroll
  for (int i = 0; i < 4; i++)
#pragma unroll
    for (int j = 0; j < 4; j++) {
      int col = colbase + j * 16;
#pragma unroll
      for (int r = 0; r < 4; r++)
        st_out(&Cb[(long)(rowbase + i * 16 + r) * ldc + col], acc[i][j][r]);
    }
}

// Small rectangular GEMM (used for NT), XCD-contiguous remap
template<typename OutT>
__global__ __launch_bounds__(256, 2)
void gemm_rect(const u16* __restrict__ A, int lda, long sA,
               const u16* __restrict__ Bt, int ldb, long sB,
               OutT* __restrict__ C, int ldc, long sC, int K,
               int l2gx, int nO8s)
{
  int L = blockIdx.x;
  int t = ((L & 7) << nO8s) | (L >> 3);
  int bx = t & ((1 << l2gx) - 1), by = t >> l2gx;
  gemm_core<OutT>(A, lda, sA, Bt, ldb, sB, C, ldc, sC, K, bx, by, blockIdx.y, threadIdx.x);
}

// Causal S = Y @ x^T -> bf16 scores (scale pre-folded into Wq). 136 tiles/batch.
// 2x2 super-block triangle walk (R3-best): per-XCD working set ~1 MB (L2-fit).
__global__ __launch_bounds__(256, 2)
void gemm_tri(const u16* __restrict__ A, int lda, long sA,
              const u16* __restrict__ Bt, int ldb, long sB,
              u16* __restrict__ C, int ldc, long sC, int K)
{
  int tp = blockIdx.x;                       // 0..135
  int g = (tp & 7) * 17 + (tp >> 3);         // 17 contiguous slots per XCD
  int sr = 0, sc = 0, pre = 0;
  for (;;) {
    int sz = (sr == sc) ? 3 : 4;
    if (pre + sz > g) break;
    pre += sz; ++sc;
    if (sc > sr) { ++sr; sc = 0; }
  }
  int w = g - pre;
  int r, c;
  if (sr == sc) { r = 2 * sr + (w > 0); c = 2 * sc + (w == 2); }
  else          { r = 2 * sr + (w >> 1); c = 2 * sc + (w & 1); }
  gemm_core<u16>(A, lda, sA, Bt, ldb, sB, C, ldc, sC, K, c, r, blockIdx.y, threadIdx.x);
}

// O = P @ V via VT (per-batch layout [B][D][T], ldb=2048 -> 4 KB row stride).
// Causal K-trim; XCD j runs long row (15-j) FIRST, then row j.
__global__ __launch_bounds__(256, 2)
void gemm_opv(const u16* __restrict__ P, int lda, long sA,
              const u16* __restrict__ VT, int ldb, long sB,
              float* __restrict__ C, int ldc, long sC)
{
  int L = blockIdx.x;                        // 0..127
  int j = L & 7, s = L >> 3;
  int by = (s < 8) ? 15 - j : j;
  int bx = s & 7;
  gemm_core<float>(P, lda, sA, VT, ldb, sB, C, ldc, sC,
                   (by + 1) * TILE, bx, by, blockIdx.y, threadIdx.x);
}

// ---------------------------------------------------------------------------
// 256x256-tile, BK=64, 8-wave, 8-phase counted-vmcnt core (R9: asm ds_reads
// + sched_barrier(0) after each lgkmcnt(0) — same fix as the 128^2 core).
// ---------------------------------------------------------------------------
template<typename OutT>
__device__ __forceinline__ void gemm_core256(
    const u16* __restrict__ A, int lda, long sA,
    const u16* __restrict__ Bt, int ldb, long sB,
    OutT* __restrict__ C, int ldc, long sC,
    int kmax, int bx, int by, int bz, int tid, u16* lds)
{
  const u16* Ab = A + bz * sA + (long)by * 256 * lda;
  const u16* Bb = Bt + bz * sB + (long)bx * 256 * ldb;

  const int lane = tid & 63, wid = tid >> 6;
  const int wm = wid >> 2;
  const int wn = wid & 3;
  const int l15 = lane & 15, q = lane >> 4;

  const int cc0 = tid, cc1 = tid + 512;
  const int r0 = cc0 >> 3, g0 = (cc0 & 7) ^ (r0 & 7);
  const int r1 = cc1 >> 3, g1 = (cc1 & 7) ^ (r1 & 7);

  const int NK = kmax >> 6;

  floatx4 acc[8][4] = {};

  auto STAGE_A = [&](int k, int half, int buf) {
    const u16* g = Ab + (long)(half * 128) * lda + k * 64;
    load16(g + (long)r0 * lda + g0 * 8, lds + buf + half * 8192 + cc0 * 8);
    load16(g + (long)r1 * lda + g1 * 8, lds + buf + half * 8192 + cc1 * 8);
  };
  auto STAGE_B = [&](int k, int half, int buf) {
    const u16* g = Bb + (long)(half * 128) * ldb + k * 64;
    load16(g + (long)r0 * ldb + g0 * 8, lds + buf + 16384 + half * 8192 + cc0 * 8);
    load16(g + (long)r1 * ldb + g1 * 8, lds + buf + 16384 + half * 8192 + cc1 * 8);
  };

  STAGE_B(0, 0, 0); STAGE_B(0, 1, 0);
  STAGE_A(0, 0, 0); STAGE_A(0, 1, 0);
  if (NK > 1) {
    STAGE_B(1, 0, 32768); STAGE_B(1, 1, 32768);
    STAGE_A(1, 0, 32768);
    asm volatile("s_waitcnt vmcnt(6)" ::: "memory");
  } else {
    asm volatile("s_waitcnt vmcnt(0)" ::: "memory");
  }
  __builtin_amdgcn_s_barrier();

  const int s0 = (q ^ (l15 & 7)) * 8;
  const int s1 = ((q + 4) ^ (l15 & 7)) * 8;

  bf16x8 aL[2][4], aH[2][4], bL[2][2], bH[2][2];

  for (int t = 0; t < NK; ++t) {
    const int buf = (t & 1) ? 32768 : 0;
    const int nbuf = 32768 - buf;
    const int abase = buf + wm * 8192 + l15 * 64;
    const int bbase = buf + 16384 + (wn >> 1) * 8192 + ((wn & 1) * 64 + l15) * 64;

    // ---- P1: read aL(8)+bL(4) | stage A1(t+1)->nbuf | MFMA Q1 acc[0-3][0-1]
#pragma unroll
    for (int i = 0; i < 4; ++i) {
      aL[0][i] = ldsread(&lds[abase + i * 1024 + s0]);
      aL[1][i] = ldsread(&lds[abase + i * 1024 + s1]);
    }
#pragma unroll
    for (int j = 0; j < 2; ++j) {
      bL[0][j] = ldsread(&lds[bbase + j * 1024 + s0]);
      bL[1][j] = ldsread(&lds[bbase + j * 1024 + s1]);
    }
    if (t + 1 < NK) STAGE_A(t + 1, 1, nbuf);
    asm volatile("s_waitcnt lgkmcnt(8)" ::: "memory");
    __builtin_amdgcn_s_barrier();
    asm volatile("s_waitcnt lgkmcnt(0)" ::: "memory");
    __builtin_amdgcn_sched_barrier(0);
    __builtin_amdgcn_s_setprio(1);
#pragma unroll
    for (int kp = 0; kp < 2; ++kp)
#pragma unroll
      for (int i = 0; i < 4; ++i)
#pragma unroll
        for (int j = 0; j < 2; ++j)
          acc[i][j] = __builtin_amdgcn_mfma_f32_16x16x32_bf16(aL[kp][i], bL[kp][j], acc[i][j], 0, 0, 0);
    __builtin_amdgcn_s_setprio(0);
    asm volatile("" ::: "memory");
    __builtin_amdgcn_s_barrier();

    // ---- P2: read bH(4) | MFMA Q2 acc[0-3][2-3]
#pragma unroll
    for (int j = 0; j < 2; ++j) {
      bH[0][j] = ldsread(&lds[bbase + (2 + j) * 1024 + s0]);
      bH[1][j] = ldsread(&lds[bbase + (2 + j) * 1024 + s1]);
    }
    asm volatile("" ::: "memory");
    __builtin_amdgcn_s_barrier();
    asm volatile("s_waitcnt lgkmcnt(0)" ::: "memory");
    __builtin_amdgcn_sched_barrier(0);
    __builtin_amdgcn_s_setprio(1);
#pragma unroll
    for (int kp = 0; kp < 2; ++kp)
#pragma unroll
      for (int i = 0; i < 4; ++i)
#pragma unroll
        for (int j = 0; j < 2; ++j)
          acc[i][2 + j] = __builtin_amdgcn_mfma_f32_16x16x32_bf16(aL[kp][i], bH[kp][j], acc[i][2 + j], 0, 0, 0);
    __builtin_amdgcn_s_setprio(0);
    asm volatile("" ::: "memory");
    __builtin_amdgcn_s_barrier();

    // ---- P3: read aH(8) | stage B0,B1(t+2)->buf | MFMA Q3 acc[4-7][2-3]
#pragma unroll
    for (int i = 0; i < 4; ++i) {
      aH[0][i] = ldsread(&lds[abase + 4096 + i * 1024 + s0]);
      aH[1][i] = ldsread(&lds[abase + 4096 + i * 1024 + s1]);
    }
    if (t + 2 < NK) { STAGE_B(t + 2, 0, buf); STAGE_B(t + 2, 1, buf); }
    asm volatile("" ::: "memory");
    __builtin_amdgcn_s_barrier();
    asm volatile("s_waitcnt lgkmcnt(0)" ::: "memory");
    __builtin_amdgcn_sched_barrier(0);
    __builtin_amdgcn_s_setprio(1);
#pragma unroll
    for (int kp = 0; kp < 2; ++kp)
#pragma unroll
      for (int i = 0; i < 4; ++i)
#pragma unroll
        for (int j = 0; j < 2; ++j)
          acc[4 + i][2 + j] = __builtin_amdgcn_mfma_f32_16x16x32_bf16(aH[kp][i], bH[kp][j], acc[4 + i][2 + j], 0, 0, 0);
    __builtin_amdgcn_s_setprio(0);
    asm volatile("" ::: "memory");
    __builtin_amdgcn_s_barrier();

    // ---- P4: stage A0(t+2)->buf | counted vmcnt | MFMA Q4 acc[4-7][0-1]
    if (t + 2 < NK) {
      STAGE_A(t + 2, 0, buf);
      asm volatile("s_waitcnt vmcnt(6)" ::: "memory");
    } else {
      asm volatile("s_waitcnt vmcnt(0)" ::: "memory");
    }
    __builtin_amdgcn_s_barrier();
    __builtin_amdgcn_s_setprio(1);
#pragma unroll
    for (int kp = 0; kp < 2; ++kp)
#pragma unroll
      for (int i = 0; i < 4; ++i)
#pragma unroll
        for (int j = 0; j < 2; ++j)
          acc[4 + i][j] = __builtin_amdgcn_mfma_f32_16x16x32_bf16(aH[kp][i], bL[kp][j], acc[4 + i][j], 0, 0, 0);
    __builtin_amdgcn_s_setprio(0);
    asm volatile("" ::: "memory");
    __builtin_amdgcn_s_barrier();
  }

  OutT* Cb = C + bz * sC;
  const int colbase = bx * 256 + wn * 64 + l15;
  const int rowbase = by * 256 + wm * 128 + (q << 2);
#pragma unroll
  for (int i = 0; i < 8; ++i)
#pragma unroll
    for (int j = 0; j < 4; ++j) {
      const int col = colbase + j * 16;
#pragma unroll
      for (int r = 0; r < 4; ++r)
        st_out(&Cb[(long)(rowbase + i * 16 + r) * ldc + col], acc[i][j][r]);
    }
}

// Merged projections on the 256^2 8-phase core.
// t<256: Y = xb @ NT^T. t>=256: VT = WvT @ xb^T with per-batch VT layout
// [B][D][T] (b = tile>>3, bx = tile&7, ldc = 2048).
__global__ __launch_bounds__(512, 2)
void gemm256_proj(const u16* __restrict__ xb, const u16* __restrict__ NT,
                  const u16* __restrict__ WvT, u16* __restrict__ Yb,
                  u16* __restrict__ VT)
{
  extern __shared__ u16 lds[];
  const int T = 2048, D = 1024;
  int L = blockIdx.x;                  // 0..511
  int t = ((L & 7) << 6) | (L >> 3);   // 64 contiguous tiles per XCD
  if (t < 256) {
    int bx = t & 3, by = t >> 2;
    gemm_core256<u16>(xb, 1024, 0L, NT, 1024, 0L, Yb, 1024, 0L,
                      1024, bx, by, 0, (int)threadIdx.x, lds);
  } else {
    int tt = t - 256;
    int bt = tt & 63, by = tt >> 6;
    int b = bt >> 3, bx = bt & 7;
    gemm_core256<u16>(WvT, 1024, 0L, xb + (long)b * T * D, 1024, 0L,
                      VT + (long)b * D * T, 2048, 0L,
                      1024, bx, by, 0, (int)threadIdx.x, lds);
  }
}

// ---------------------------------------------------------------------------
// Merged input converts: linear x/Wq/Wk casts AND the Wv transpose in one
// dispatch. Branch is block-uniform (barriers only in the transpose path).
// ---------------------------------------------------------------------------
__global__ __launch_bounds__(256)
void cvt_all(const float4* __restrict__ x, const float4* __restrict__ Wq,
             const float4* __restrict__ Wk, const float* __restrict__ Wv,
             u16* __restrict__ xb, u16* __restrict__ oq, u16* __restrict__ ok,
             u16* __restrict__ wvt, int n4x, int n4w, int nb_lin)
{
  const int D = 1024;
  if ((int)blockIdx.x < nb_lin) {
    int i = blockIdx.x * 256 + threadIdx.x;
    const float4* src; u16* dst; int k; float scale;
    if (i < n4x)               { src = x;  dst = xb; k = i;             scale = 1.0f; }
    else if (i < n4x + n4w)    { src = Wq; dst = oq; k = i - n4x;       scale = 0.03125f; }
    else if (i < n4x + 2*n4w)  { src = Wk; dst = ok; k = i - n4x - n4w; scale = 1.0f; }
    else return;
    float4 v = src[k];
    ushort4 r;
    r.x = f2bf(v.x * scale); r.y = f2bf(v.y * scale);
    r.z = f2bf(v.z * scale); r.w = f2bf(v.w * scale);
    *(ushort4*)(dst + (long)k * 4) = r;
  } else {
    // Wv (d_in x d_out) fp32 -> WvT (d_out x d_in) bf16, LDS tiled
    __shared__ float t[64][65];
    int bb = blockIdx.x - nb_lin;            // 0..255
    int tid = threadIdx.x;
    int c = tid & 63, r = tid >> 6;
    int e0 = (bb & 15) * 64, d0 = (bb >> 4) * 64;
    for (int rr = r; rr < 64; rr += 4)
      t[rr][c] = Wv[(long)(d0 + rr) * D + e0 + c];
    __syncthreads();
    for (int rr = r; rr < 64; rr += 4)
      wvt[(long)(e0 + rr) * D + d0 + c] = f2bf(t[c][rr]);
  }
}

// ---------------------------------------------------------------------------
// Wave-per-row causal softmax: one 64-lane wave owns a whole row in registers,
// reductions via __shfl_xor — no LDS, no barriers. Trimmed window W; [n, W)
// written as zeros (opv reads it).
// ---------------------------------------------------------------------------
__global__ __launch_bounds__(256)
void softmax_wave(u16* __restrict__ S)
{
  const int T = 2048;
  int gr = blockIdx.x * 4 + (threadIdx.x >> 6);   // global row id (bi*T + row)
  int lane = threadIdx.x & 63;
  int row = gr & (T - 1);
  u16* Prow = S + (long)gr * T;
  int n = row + 1;
  int W = ((row >> 7) + 1) << 7;

  float v[4][8];
  float lmax = -3.0e38f;
#pragma unroll
  for (int c = 0; c < 4; c++) {
    int i0 = c * 512 + lane * 8;
    if (i0 < W) {
      u16x8 pv = *(const u16x8*)(Prow + i0);
#pragma unroll
      for (int j = 0; j < 8; j++) {
        float f = (i0 + j < n) ? bf2f(pv[j]) : -3.0e38f;
        v[c][j] = f;
        lmax = fmaxf(lmax, f);
      }
    }
  }
#pragma unroll
  for (int o = 32; o > 0; o >>= 1) lmax = fmaxf(lmax, __shfl_xor(lmax, o, 64));

  float lsum = 0.f;
#pragma unroll
  for (int c = 0; c < 4; c++) {
    int i0 = c * 512 + lane * 8;
    if (i0 < W) {
#pragma unroll
      for (int j = 0; j < 8; j++) {
        float e = (i0 + j < n) ? __expf(v[c][j] - lmax) : 0.f;
        v[c][j] = e;
        lsum += e;
      }
    }
  }
#pragma unroll
  for (int o = 32; o > 0; o >>= 1) lsum += __shfl_xor(lsum, o, 64);
  float inv = 1.0f / lsum;

#pragma unroll
  for (int c = 0; c < 4; c++) {
    int i0 = c * 512 + lane * 8;
    if (i0 < W) {
      u16x8 w;
#pragma unroll
      for (int j = 0; j < 8; j++) w[j] = f2bf(v[c][j] * inv);
      *(u16x8*)(Prow + i0) = w;
    }
  }
}

extern "C" void kernel_launch(void* const* d_in, const int* in_sizes, int n_in,
                              void* d_out, int out_size, void* d_ws, size_t ws_size,
                              hipStream_t stream)
{
  const int B = 8, T = 2048, D = 1024;
  const float* x  = (const float*)d_in[0];
  const float* Wq = (const float*)d_in[1];
  const float* Wk = (const float*)d_in[2];
  const float* Wv = (const float*)d_in[3];
  float* out = (float*)d_out;
  char* ws = (char*)d_ws;

  // layout (MB): xb 0-32 | WvT 32-34 | NT 34-36 | Yb 36-68 (Wqb@36,Wkb@38 dead
  // after NT gemm) | VT 68-100 ([B][D][T] per-batch) | S bf16 @100 (8 MB/batch)
  u16* xb  = (u16*)(ws);
  u16* WvT = (u16*)(ws + (32ul << 20));
  u16* NT  = (u16*)(ws + (34ul << 20));
  u16* Yb  = (u16*)(ws + (36ul << 20));
  u16* Wqb = Yb;                            // transient
  u16* Wkb = (u16*)(ws + (38ul << 20));     // transient
  u16* VT  = (u16*)(ws + (68ul << 20));
  u16* S   = (u16*)(ws + (100ul << 20));

  const size_t OFF_S = 100ul << 20;
  int NB = 8;
  while (NB > 1 && OFF_S + (size_t)NB * T * T * 2 > ws_size) NB >>= 1;

  // one-time: allow 128 KiB dynamic LDS for the 8-phase core
  static bool attr_done = false;
  if (!attr_done) {
    hipFuncSetAttribute(reinterpret_cast<const void*>(gemm256_proj),
                        hipFuncAttributeMaxDynamicSharedMemorySize, 131072);
    attr_done = true;
  }

  int n4x = B * T * D / 4, n4w = D * D / 4;
  int nb_lin = (n4x + 2 * n4w + 255) / 256;   // 18432
  cvt_all<<<nb_lin + 256, 256, 0, stream>>>(
      (const float4*)x, (const float4*)Wq, (const float4*)Wk, Wv,
      xb, Wqb, Wkb, WvT, n4x, n4w, nb_lin);

  // NT[d',d] = sum_e Wk[d',e] Wq'[d,e]   (scale folded into Wq')
  gemm_rect<u16><<<dim3(64, 1), 256, 0, stream>>>(
      Wkb, D, 0L, Wqb, D, 0L, NT, D, 0L, D, 3, 3);
  // Y = xb @ NT^T  and  VT = WvT @ xb^T (per-batch layout) in one dispatch
  gemm256_proj<<<dim3(512, 1), 512, 131072, stream>>>(xb, NT, WvT, Yb, VT);

  for (int b0 = 0; b0 < B; b0 += NB) {
    gemm_tri<<<dim3(136, NB), 256, 0, stream>>>(
        Yb + (long)b0 * T * D, D, (long)T * D,
        xb + (long)b0 * T * D, D, (long)T * D,
        S, T, (long)T * T, D);
    softmax_wave<<<NB * T / 4, 256, 0, stream>>>(S);
    gemm_opv<<<dim3(128, NB), 256, 0, stream>>>(
        S, T, (long)T * T,
        VT + (long)b0 * D * T, 2048, (long)D * T,
        out + (long)b0 * T * D, D, (long)T * D);
  }
}